// Round 2
// baseline (257.552 us; speedup 1.0000x reference)
//
#include <hip/hip_runtime.h>
#include <math.h>

typedef __attribute__((ext_vector_type(8))) short s16x8;
typedef __attribute__((ext_vector_type(4))) short s16x4;
typedef __attribute__((ext_vector_type(4))) float f32x4;

#define DEV __device__ __forceinline__

DEV float b2f(unsigned short u){ unsigned int x = ((unsigned int)u)<<16u; return __builtin_bit_cast(float,x); }
DEV unsigned short f2b(float f){
  unsigned int x = __builtin_bit_cast(unsigned int,f);
  x += 0x7fffu + ((x>>16)&1u);
  return (unsigned short)(x>>16);
}

// dims
#define TTOK 32768   // 2*128*128 tokens
#define CCH  192
#define NHD  6
#define HDD  32

// ---------------- K0: weight transpose->bf16 + bias table ----------------
__global__ __launch_bounds__(256) void prep_w(
    const float* __restrict__ qkvw, const float* __restrict__ dprojw,
    const float* __restrict__ projw, const float* __restrict__ fc1w,
    const float* __restrict__ fc2w, const int* __restrict__ rpi,
    const float* __restrict__ rpb,
    unsigned short* kvw, unsigned short* dpw, unsigned short* pjw,
    unsigned short* f1w, unsigned short* f2w, unsigned short* bt){
  int i = blockIdx.x*256 + threadIdx.x;
  if(i < 73728){                       // kvw [384][192] = qkv_w[:,192+n]
    int n = i/192, k = i - n*192;
    kvw[i] = f2b(qkvw[k*576 + 192 + n]);
  } else if(i < 110592){               // dpw [192][192]: dproj_w is already [out][in] (einsum 'oi')
    int j = i - 73728;
    dpw[j] = f2b(dprojw[j]);
  } else if(i < 147456){               // pjw [192][192]
    int j = i - 110592; int n = j/192, k = j - n*192;
    pjw[j] = f2b(projw[k*192 + n]);
  } else if(i < 221184){               // f1w [384][192]
    int j = i - 147456; int n = j/192, k = j - n*192;
    f1w[j] = f2b(fc1w[k*384 + n]);
  } else if(i < 294912){               // f2w [192][384]
    int j = i - 221184; int n = j/384, k = j - n*384;
    f2w[j] = f2b(fc2w[k*192 + n]);
  } else {                             // bias_t [h][k=576][q=256]
    int j = i - 294912;
    int h = j/147456; int rr = j - h*147456;
    int kk = rr >> 8; int q = rr & 255;
    bt[j] = f2b(rpb[rpi[q*576 + kk]*6 + h]);
  }
}

// ---------------- K1: x,depth NCHW -> token-major bf16 (+LN1 on x) ----------------
__global__ __launch_bounds__(256) void prep_x(
    const float* __restrict__ x, const float* __restrict__ depth,
    const float* __restrict__ g, const float* __restrict__ be,
    unsigned short* xn, unsigned short* xf, unsigned short* dn){
  __shared__ float t[64][193];
  __shared__ float ps[4][64], pq[4][64];
  __shared__ float mu_s[64], rs_s[64];
  int tid = threadIdx.x;
  long tokbase = (long)blockIdx.x * 64;
  int b = (int)(tokbase >> 14); int hw = (int)(tokbase & 16383);
  const float* xb = x + ((long)b*192)*16384 + hw;
  int tok = tid & 63, cpart = tid >> 6;
  for(int c = cpart; c < 192; c += 4) t[tok][c] = xb[(long)c*16384 + tok];
  __syncthreads();
  float s = 0.f, q = 0.f;
  #pragma unroll 4
  for(int i = 0; i < 48; i++){ float v = t[tok][cpart*48 + i]; s += v; q += v*v; }
  ps[cpart][tok] = s; pq[cpart][tok] = q;
  __syncthreads();
  if(tid < 64){
    float ss = ps[0][tid]+ps[1][tid]+ps[2][tid]+ps[3][tid];
    float qq = pq[0][tid]+pq[1][tid]+pq[2][tid]+pq[3][tid];
    float mu = ss * (1.f/192.f);
    float var = qq * (1.f/192.f) - mu*mu;
    mu_s[tid] = mu; rs_s[tid] = 1.f/sqrtf(var + 1e-5f);
  }
  __syncthreads();
  long obase = tokbase * 192;
  for(int u = tid; u < 64*192; u += 256){
    int tk = u / 192, ch = u - tk*192;
    float v = t[tk][ch];
    xf[obase + u] = f2b(v);
    xn[obase + u] = f2b((v - mu_s[tk]) * rs_s[tk] * g[ch] + be[ch]);
  }
  __syncthreads();
  const float* db = depth + ((long)b*192)*16384 + hw;
  for(int c = cpart; c < 192; c += 4) t[tok][c] = db[(long)c*16384 + tok];
  __syncthreads();
  for(int u = tid; u < 64*192; u += 256){
    int tk = u / 192, ch = u - tk*192;
    dn[obase + u] = f2b(t[tk][ch]);
  }
}

// ---------------- GEMM: C[M=32768][N] = A[M][K] @ Wt[N][K]^T + bias (+res, gelu) ----------------
// block 256 = 4 waves (2x2), tile 128x64, BK=64
__global__ __launch_bounds__(256) void gemm_k(
    const unsigned short* __restrict__ A, const unsigned short* __restrict__ W,
    const float* __restrict__ bias, const unsigned short* __restrict__ resb,
    const float* __restrict__ resf, void* outp, int K, int N, int flags){
  __shared__ unsigned short Al[128*72];
  __shared__ unsigned short Bl[64*72];
  int tid = threadIdx.x;
  int lane = tid & 63, wv = tid >> 6;
  int wm = wv >> 1, wn = wv & 1;
  int l15 = lane & 15, lg = lane >> 4;
  long rowbase = (long)blockIdx.x * 128;
  int colbase = blockIdx.y * 64;
  f32x4 acc[4][2];
  #pragma unroll
  for(int m=0;m<4;m++)
    #pragma unroll
    for(int n=0;n<2;n++) acc[m][n] = (f32x4){0.f,0.f,0.f,0.f};
  int nk = K >> 6;
  for(int kt = 0; kt < nk; kt++){
    int k0 = kt*64;
    #pragma unroll
    for(int i = 0; i < 4; i++){
      int u = i*256 + tid; int r = u >> 3, c = u & 7;
      s16x8 v = *(const s16x8*)(A + (rowbase + r)*(long)K + k0 + c*8);
      *(s16x8*)(Al + r*72 + c*8) = v;
    }
    #pragma unroll
    for(int i = 0; i < 2; i++){
      int u = i*256 + tid; int r = u >> 3, c = u & 7;
      s16x8 v = *(const s16x8*)(W + (long)(colbase + r)*K + k0 + c*8);
      *(s16x8*)(Bl + r*72 + c*8) = v;
    }
    __syncthreads();
    #pragma unroll
    for(int kk = 0; kk < 64; kk += 32){
      s16x8 af[4], bf[2];
      #pragma unroll
      for(int m = 0; m < 4; m++) af[m] = *(const s16x8*)(Al + (wm*64 + m*16 + l15)*72 + kk + lg*8);
      #pragma unroll
      for(int n = 0; n < 2; n++) bf[n] = *(const s16x8*)(Bl + (wn*32 + n*16 + l15)*72 + kk + lg*8);
      #pragma unroll
      for(int m = 0; m < 4; m++)
        #pragma unroll
        for(int n = 0; n < 2; n++)
          acc[m][n] = __builtin_amdgcn_mfma_f32_16x16x32_bf16(af[m], bf[n], acc[m][n], 0, 0, 0);
    }
    __syncthreads();
  }
  // epilogue
  #pragma unroll
  for(int n = 0; n < 2; n++){
    int colg = colbase + wn*32 + n*16 + l15;
    float bs = bias[colg];
    #pragma unroll
    for(int m = 0; m < 4; m++){
      long rowg = rowbase + wm*64 + m*16 + lg*4;
      #pragma unroll
      for(int r = 0; r < 4; r++){
        long idx = (rowg + r)*(long)N + colg;
        float v = acc[m][n][r] + bs;
        if(flags & 1) v = 0.5f*v*(1.f + erff(v*0.70710678118f));
        if(resb) v += b2f(resb[idx]);
        if(resf) v += resf[idx];
        if(flags & 2) ((float*)outp)[idx] = v;
        else ((unsigned short*)outp)[idx] = f2b(v);
      }
    }
  }
}

// ---------------- Attention: 1 block per (window, head), flash over 3 chunks of 192 kv ----------------
__global__ __launch_bounds__(256) void attn_k(
    const unsigned short* __restrict__ qmat, const unsigned short* __restrict__ kvmat,
    const unsigned short* __restrict__ bias_t, unsigned short* __restrict__ omat){
  __shared__ unsigned short Kl[192*40];      // [pos][d], stride 40
  __shared__ unsigned short Vl[32*200];      // [d][pos], stride 200 (transposed)
  __shared__ unsigned short QP[4][64*40];    // per-wave: Q staging, then P^T [q][k]
  int tid = threadIdx.x, lane = tid & 63, wv = tid >> 6;
  int l15 = lane & 15, lg = lane >> 4;
  int bid = blockIdx.x;
  int win = bid / 6, h = bid - win*6;
  int b = win >> 6, wi = (win >> 3) & 7, wj = win & 7;
  const float scale = 0.17677669529663687f;  // 32^-0.5

  // stage this wave's 64 q rows (scaled) into QP[wv]
  #pragma unroll
  for(int i = 0; i < 4; i++){
    int u = i*64 + lane; int r = u >> 2, c = u & 3;
    int qr = wv*64 + r;
    long tok = (long)b*16384 + (wi*16 + (qr >> 4))*128 + wj*16 + (qr & 15);
    s16x8 v = *(const s16x8*)(qmat + tok*192 + h*32 + c*8);
    s16x8 o;
    #pragma unroll
    for(int j = 0; j < 8; j++) o[j] = (short)f2b(b2f((unsigned short)v[j]) * scale);
    *(s16x8*)(&QP[wv][r*40 + c*8]) = o;
  }
  s16x8 qb[4];
  #pragma unroll
  for(int nt = 0; nt < 4; nt++) qb[nt] = *(const s16x8*)(&QP[wv][(nt*16 + l15)*40 + lg*8]);

  float m_run[4], l_run[4];
  #pragma unroll
  for(int nt = 0; nt < 4; nt++){ m_run[nt] = -1e30f; l_run[nt] = 0.f; }
  f32x4 oacc[2][4];
  #pragma unroll
  for(int mt = 0; mt < 2; mt++)
    #pragma unroll
    for(int nt = 0; nt < 4; nt++) oacc[mt][nt] = (f32x4){0.f,0.f,0.f,0.f};

  for(int ch = 0; ch < 3; ch++){
    __syncthreads();
    // stage K,V chunk (192 positions), zero-fill out-of-image
    #pragma unroll
    for(int i = 0; i < 3; i++){
      int u = i*256 + tid; int p = u >> 2, c = u & 3;
      int gp = ch*192 + p; int ii = gp / 24, jj = gp - ii*24;
      int gr = wi*16 - 4 + ii, gc = wj*16 - 4 + jj;
      bool ok = (gr >= 0) && (gr < 128) && (gc >= 0) && (gc < 128);
      s16x8 vk = (s16x8){0,0,0,0,0,0,0,0};
      s16x8 vv = (s16x8){0,0,0,0,0,0,0,0};
      if(ok){
        long tok = (long)b*16384 + gr*128 + gc;
        vk = *(const s16x8*)(kvmat + tok*384 + h*32 + c*8);
        vv = *(const s16x8*)(kvmat + tok*384 + 192 + h*32 + c*8);
      }
      *(s16x8*)(Kl + p*40 + c*8) = vk;
      #pragma unroll
      for(int j = 0; j < 8; j++) Vl[(c*8 + j)*200 + p] = (unsigned short)vv[j];
    }
    __syncthreads();
    #pragma unroll 1
    for(int kt = 0; kt < 6; kt++){
      int kb = kt*32;
      s16x8 ka[2];
      #pragma unroll
      for(int mt = 0; mt < 2; mt++) ka[mt] = *(const s16x8*)(Kl + (kb + mt*16 + l15)*40 + lg*8);
      f32x4 zero = (f32x4){0.f,0.f,0.f,0.f};
      f32x4 s[2][4];
      #pragma unroll
      for(int mt = 0; mt < 2; mt++)
        #pragma unroll
        for(int nt = 0; nt < 4; nt++)
          s[mt][nt] = __builtin_amdgcn_mfma_f32_16x16x32_bf16(ka[mt], qb[nt], zero, 0, 0, 0);
      // bias add: bias_t[h][kglob][qglob]
      int kgb = ch*192 + kb;
      #pragma unroll
      for(int mt = 0; mt < 2; mt++){
        int kg0 = kgb + mt*16 + lg*4;
        #pragma unroll
        for(int nt = 0; nt < 4; nt++){
          int qg = wv*64 + nt*16 + l15;
          const unsigned short* bp = bias_t + ((long)h*576 + kg0)*256 + qg;
          #pragma unroll
          for(int r = 0; r < 4; r++) s[mt][nt][r] += b2f(bp[r*256]);
        }
      }
      // online softmax per q-column
      float fac[4];
      #pragma unroll
      for(int nt = 0; nt < 4; nt++){
        float lm = fmaxf(fmaxf(fmaxf(s[0][nt][0], s[0][nt][1]), fmaxf(s[0][nt][2], s[0][nt][3])),
                         fmaxf(fmaxf(s[1][nt][0], s[1][nt][1]), fmaxf(s[1][nt][2], s[1][nt][3])));
        lm = fmaxf(lm, __shfl_xor(lm, 16));
        lm = fmaxf(lm, __shfl_xor(lm, 32));
        float nm = fmaxf(m_run[nt], lm);
        fac[nt] = __expf(m_run[nt] - nm);
        m_run[nt] = nm;
        l_run[nt] *= fac[nt];
      }
      #pragma unroll
      for(int mt = 0; mt < 2; mt++)
        #pragma unroll
        for(int nt = 0; nt < 4; nt++)
          #pragma unroll
          for(int r = 0; r < 4; r++) oacc[mt][nt][r] *= fac[nt];
      // P = exp(S - m), write P^T to QP[wv] as [q][k]
      #pragma unroll
      for(int mt = 0; mt < 2; mt++)
        #pragma unroll
        for(int nt = 0; nt < 4; nt++){
          int q = nt*16 + l15;
          #pragma unroll
          for(int r = 0; r < 4; r++){
            float p = __expf(s[mt][nt][r] - m_run[nt]);
            l_run[nt] += p;
            QP[wv][q*40 + mt*16 + lg*4 + r] = f2b(p);
          }
        }
      // PV: O^T += V^T @ P^T
      s16x8 va[2], pb[4];
      #pragma unroll
      for(int mt = 0; mt < 2; mt++) va[mt] = *(const s16x8*)(Vl + (mt*16 + l15)*200 + kb + lg*8);
      #pragma unroll
      for(int nt = 0; nt < 4; nt++) pb[nt] = *(const s16x8*)(&QP[wv][(nt*16 + l15)*40 + lg*8]);
      #pragma unroll
      for(int mt = 0; mt < 2; mt++)
        #pragma unroll
        for(int nt = 0; nt < 4; nt++)
          oacc[mt][nt] = __builtin_amdgcn_mfma_f32_16x16x32_bf16(va[mt], pb[nt], oacc[mt][nt], 0, 0, 0);
    }
  }
  // finalize
  #pragma unroll
  for(int nt = 0; nt < 4; nt++){
    float l = l_run[nt];
    l += __shfl_xor(l, 16);
    l += __shfl_xor(l, 32);
    l_run[nt] = 1.f / l;
  }
  #pragma unroll
  for(int nt = 0; nt < 4; nt++){
    int qr = wv*64 + nt*16 + l15;
    long tok = (long)b*16384 + (wi*16 + (qr >> 4))*128 + wj*16 + (qr & 15);
    #pragma unroll
    for(int mt = 0; mt < 2; mt++){
      s16x4 o;
      #pragma unroll
      for(int r = 0; r < 4; r++) o[r] = (short)f2b(oacc[mt][nt][r] * l_run[nt]);
      *(s16x4*)(omat + tok*192 + h*32 + mt*16 + lg*4) = o;
    }
  }
}

// ---------------- LN2: r2 (f32 token-major) -> n2 bf16 ----------------
__global__ __launch_bounds__(256) void ln2_k(
    const float* __restrict__ in, const float* __restrict__ g,
    const float* __restrict__ be, unsigned short* __restrict__ out){
  __shared__ float t[64][193];
  __shared__ float ps[4][64], pq[4][64];
  __shared__ float mu_s[64], rs_s[64];
  int tid = threadIdx.x;
  long tokbase = (long)blockIdx.x * 64;
  long base = tokbase * 192;
  for(int u = tid; u < 64*192; u += 256){
    int tk = u / 192, ch = u - tk*192;
    t[tk][ch] = in[base + u];
  }
  __syncthreads();
  int tok = tid & 63, cpart = tid >> 6;
  float s = 0.f, q = 0.f;
  #pragma unroll 4
  for(int i = 0; i < 48; i++){ float v = t[tok][cpart*48 + i]; s += v; q += v*v; }
  ps[cpart][tok] = s; pq[cpart][tok] = q;
  __syncthreads();
  if(tid < 64){
    float ss = ps[0][tid]+ps[1][tid]+ps[2][tid]+ps[3][tid];
    float qq = pq[0][tid]+pq[1][tid]+pq[2][tid]+pq[3][tid];
    float mu = ss * (1.f/192.f);
    float var = qq * (1.f/192.f) - mu*mu;
    mu_s[tid] = mu; rs_s[tid] = 1.f/sqrtf(var + 1e-5f);
  }
  __syncthreads();
  for(int u = tid; u < 64*192; u += 256){
    int tk = u / 192, ch = u - tk*192;
    out[base + u] = f2b((t[tk][ch] - mu_s[tk]) * rs_s[tk] * g[ch] + be[ch]);
  }
}

// ---------------- final transpose: ymat [T][192] f32 -> NCHW f32 ----------------
__global__ __launch_bounds__(256) void tr_out(const float* __restrict__ ym, float* __restrict__ out){
  __shared__ float t[64][193];
  int tid = threadIdx.x;
  long tokbase = (long)blockIdx.x * 64;
  for(int u = tid; u < 64*192; u += 256){
    int tk = u / 192, ch = u - tk*192;
    t[tk][ch] = ym[tokbase*192 + u];
  }
  __syncthreads();
  int b = (int)(tokbase >> 14), hw = (int)(tokbase & 16383);
  float* ob = out + (long)b*192*16384 + hw;
  int tok = tid & 63, cpart = tid >> 6;
  for(int c = cpart; c < 192; c += 4)
    ob[(long)c*16384 + tok] = t[tok][c];
}

extern "C" void kernel_launch(void* const* d_in, const int* in_sizes, int n_in,
                              void* d_out, int out_size, void* d_ws, size_t ws_size,
                              hipStream_t stream) {
  const float* x     = (const float*)d_in[0];
  const float* depth = (const float*)d_in[1];
  const int*   rpi   = (const int*)d_in[2];
  const float* n1w   = (const float*)d_in[3];
  const float* n1b   = (const float*)d_in[4];
  const float* qkvw  = (const float*)d_in[5];
  const float* qkvb  = (const float*)d_in[6];
  const float* dprjw = (const float*)d_in[7];
  const float* dprjb = (const float*)d_in[8];
  const float* rpb   = (const float*)d_in[9];
  const float* prjw  = (const float*)d_in[10];
  const float* prjb  = (const float*)d_in[11];
  const float* n2w   = (const float*)d_in[12];
  const float* n2b   = (const float*)d_in[13];
  const float* fc1w  = (const float*)d_in[14];
  const float* fc1b  = (const float*)d_in[15];
  const float* fc2w  = (const float*)d_in[16];
  const float* fc2b  = (const float*)d_in[17];

  char* ws = (char*)d_ws;
  // buffer map (bytes). Overlays: ym reuses xn+dn; h1 reuses kv; n2 reuses om; total ~110 MB
  unsigned short* xn  = (unsigned short*)(ws + 0);          // 12582912  (dead after KV gemm)
  unsigned short* dn  = (unsigned short*)(ws + 12582912);   // 12582912  (dead after Q gemm)
  float*          ym  = (float*)(ws + 0);                   // 25165824  (written fc2, read tr_out)
  unsigned short* xf  = (unsigned short*)(ws + 25165824);   // 12582912
  unsigned short* kv  = (unsigned short*)(ws + 37748736);   // 25165824  (dead after attn)
  unsigned short* h1  = (unsigned short*)(ws + 37748736);   // 25165824
  unsigned short* qm  = (unsigned short*)(ws + 62914560);   // 12582912
  float*          r2  = (float*)(ws + 75497472);            // 25165824
  unsigned short* om  = (unsigned short*)(ws + 100663296);  // 12582912  (dead after proj)
  unsigned short* n2  = (unsigned short*)(ws + 100663296);  // 12582912
  unsigned short* kvw = (unsigned short*)(ws + 113246208);  // 147456
  unsigned short* dpw = (unsigned short*)(ws + 113393664);  // 73728
  unsigned short* pjw = (unsigned short*)(ws + 113467392);  // 73728
  unsigned short* f1w = (unsigned short*)(ws + 113541120);  // 147456
  unsigned short* f2w = (unsigned short*)(ws + 113688576);  // 147456
  unsigned short* bt  = (unsigned short*)(ws + 113836032);  // 1769472 -> end 115605504

  prep_w<<<4608, 256, 0, stream>>>(qkvw, dprjw, prjw, fc1w, fc2w, rpi, rpb,
                                   kvw, dpw, pjw, f1w, f2w, bt);
  prep_x<<<512, 256, 0, stream>>>(x, depth, n1w, n1b, xn, xf, dn);
  // KV = LN1(x) @ qkv_w[:,192:576] + b
  gemm_k<<<dim3(256,6), 256, 0, stream>>>(xn, kvw, qkvb + 192, nullptr, nullptr, kv, 192, 384, 0);
  // Q = depth @ dproj_w^T + b  (dproj_w already [out][in])
  gemm_k<<<dim3(256,3), 256, 0, stream>>>(dn, dpw, dprjb, nullptr, nullptr, qm, 192, 192, 0);
  attn_k<<<768, 256, 0, stream>>>(qm, kv, bt, om);
  // r2 = attn_out @ proj_w + b + xf   (f32)
  gemm_k<<<dim3(256,3), 256, 0, stream>>>(om, pjw, prjb, xf, nullptr, r2, 192, 192, 2);
  ln2_k<<<512, 256, 0, stream>>>(r2, n2w, n2b, n2);
  // h1 = gelu(n2 @ fc1_w + b)
  gemm_k<<<dim3(256,6), 256, 0, stream>>>(n2, f1w, fc1b, nullptr, nullptr, h1, 192, 384, 1);
  // ym = h1 @ fc2_w + b + r2   (f32)
  gemm_k<<<dim3(256,3), 256, 0, stream>>>(h1, f2w, fc2b, nullptr, r2, ym, 384, 192, 2);
  tr_out<<<512, 256, 0, stream>>>(ym, (float*)d_out);
}

// Round 3
// 253.918 us; speedup vs baseline: 1.0143x; 1.0143x over previous
//
#include <hip/hip_runtime.h>
#include <math.h>

typedef __attribute__((ext_vector_type(8))) short s16x8;
typedef __attribute__((ext_vector_type(4))) short s16x4;
typedef __attribute__((ext_vector_type(4))) float f32x4;

#define DEV __device__ __forceinline__

DEV float b2f(unsigned short u){ unsigned int x = ((unsigned int)u)<<16u; return __builtin_bit_cast(float,x); }
DEV unsigned short f2b(float f){
  unsigned int x = __builtin_bit_cast(unsigned int,f);
  x += 0x7fffu + ((x>>16)&1u);
  return (unsigned short)(x>>16);
}
DEV unsigned int pk_bf16(float lo, float hi){
  unsigned int r;
  asm("v_cvt_pk_bf16_f32 %0, %1, %2" : "=v"(r) : "v"(lo), "v"(hi));
  return r;
}

// ---------------- K0: weight prep + bias table ----------------
// bias table layout: [h][k>>2][q][k&3] bf16 (8B-vector loadable per MFMA fragment)
__global__ __launch_bounds__(256) void prep_w(
    const float* __restrict__ qkvw, const float* __restrict__ dprojw,
    const float* __restrict__ projw, const float* __restrict__ fc1w,
    const float* __restrict__ fc2w, const int* __restrict__ rpi,
    const float* __restrict__ rpb,
    unsigned short* kvw, unsigned short* dpw, unsigned short* pjw,
    unsigned short* f1w, unsigned short* f2w, unsigned short* bt){
  int i = blockIdx.x*256 + threadIdx.x;
  if(i < 73728){                       // kvw [384][192] = qkv_w[:,192+n]
    int n = i/192, k = i - n*192;
    kvw[i] = f2b(qkvw[k*576 + 192 + n]);
  } else if(i < 110592){               // dpw: dproj_w already [out][in]
    int j = i - 73728;
    dpw[j] = f2b(dprojw[j]);
  } else if(i < 147456){               // pjw [192][192]
    int j = i - 110592; int n = j/192, k = j - n*192;
    pjw[j] = f2b(projw[k*192 + n]);
  } else if(i < 221184){               // f1w [384][192]
    int j = i - 147456; int n = j/192, k = j - n*192;
    f1w[j] = f2b(fc1w[k*384 + n]);
  } else if(i < 294912){               // f2w [192][384]
    int j = i - 221184; int n = j/384, k = j - n*384;
    f2w[j] = f2b(fc2w[k*192 + n]);
  } else {                             // bias_t
    int j = i - 294912;                // 0 .. 884735
    int h = j/147456; int rr = j - h*147456;
    int kk = rr >> 8; int q = rr & 255;
    bt[((h*144 + (kk>>2))*256 + q)*4 + (kk&3)] = f2b(rpb[rpi[q*576 + kk]*6 + h]);
  }
}

// ---------------- K1: x,depth NCHW -> token-major bf16 (+LN1 on x) ----------------
__global__ __launch_bounds__(256) void prep_x(
    const float* __restrict__ x, const float* __restrict__ depth,
    const float* __restrict__ g, const float* __restrict__ be,
    unsigned short* xn, unsigned short* xf, unsigned short* dn){
  __shared__ float t[64][193];
  __shared__ float ps[4][64], pq[4][64];
  __shared__ float mu_s[64], rs_s[64];
  int tid = threadIdx.x;
  long tokbase = (long)blockIdx.x * 64;
  int b = (int)(tokbase >> 14); int hw = (int)(tokbase & 16383);
  const float* xb = x + ((long)b*192)*16384 + hw;
  int tok = tid & 63, cpart = tid >> 6;
  for(int c = cpart; c < 192; c += 4) t[tok][c] = xb[(long)c*16384 + tok];
  __syncthreads();
  float s = 0.f, q = 0.f;
  #pragma unroll 4
  for(int i = 0; i < 48; i++){ float v = t[tok][cpart*48 + i]; s += v; q += v*v; }
  ps[cpart][tok] = s; pq[cpart][tok] = q;
  __syncthreads();
  if(tid < 64){
    float ss = ps[0][tid]+ps[1][tid]+ps[2][tid]+ps[3][tid];
    float qq = pq[0][tid]+pq[1][tid]+pq[2][tid]+pq[3][tid];
    float mu = ss * (1.f/192.f);
    float var = qq * (1.f/192.f) - mu*mu;
    mu_s[tid] = mu; rs_s[tid] = 1.f/sqrtf(var + 1e-5f);
  }
  __syncthreads();
  long obase = tokbase * 192;
  for(int u = tid; u < 64*192; u += 256){
    int tk = u / 192, ch = u - tk*192;
    float v = t[tk][ch];
    xf[obase + u] = f2b(v);
    xn[obase + u] = f2b((v - mu_s[tk]) * rs_s[tk] * g[ch] + be[ch]);
  }
  __syncthreads();
  const float* db = depth + ((long)b*192)*16384 + hw;
  for(int c = cpart; c < 192; c += 4) t[tok][c] = db[(long)c*16384 + tok];
  __syncthreads();
  for(int u = tid; u < 64*192; u += 256){
    int tk = u / 192, ch = u - tk*192;
    dn[obase + u] = f2b(t[tk][ch]);
  }
}

// ---------------- GEMM2: W preloaded in LDS once, A direct from global, no loop barriers ----
// block 256 = 4 waves (2x2), tile 128x64. Grid 1D XCD-swizzled: 256 m-blocks x (N/64) n-blocks.
// flags: 1=gelu, 2=f32 token-major out, 4=*attn_scale, 8=fc2 (f32 NCHW out, +resf)
__global__ __launch_bounds__(256) void gemm2(
    const unsigned short* __restrict__ A, const unsigned short* __restrict__ W,
    const float* __restrict__ bias, const unsigned short* __restrict__ resb,
    const float* __restrict__ resf, void* outp, int K, int N, int flags){
  extern __shared__ unsigned short Bl[];   // [64][K+8]
  int tid = threadIdx.x, lane = tid & 63, wv = tid >> 6;
  int wm = wv >> 1, wn = wv & 1, l15 = lane & 15, lg = lane >> 4;
  int bid = blockIdx.x;
  int X = bid & 7, j = bid >> 3;
  int mb = X + 8*(j & 31);
  int nb = j >> 5;
  long rowbase = (long)mb * 128;
  int colbase = nb * 64;
  int KS = K + 8, K8 = K >> 3;
  // preload W tile (once)
  int nv = 64 * K8;
  for(int u = tid; u < nv; u += 256){
    int row = u / K8, c = u - row*K8;
    *(s16x8*)(Bl + row*KS + c*8) = *(const s16x8*)(W + (long)(colbase + row)*K + c*8);
  }
  __syncthreads();
  const unsigned short* ap[4];
  #pragma unroll
  for(int m = 0; m < 4; m++) ap[m] = A + (rowbase + wm*64 + m*16 + l15)*(long)K + lg*8;
  f32x4 acc[4][2];
  #pragma unroll
  for(int m=0;m<4;m++)
    #pragma unroll
    for(int n=0;n<2;n++) acc[m][n] = (f32x4){0.f,0.f,0.f,0.f};
  int nkk = K >> 5;
  #pragma unroll 3
  for(int kk = 0; kk < nkk; kk++){
    s16x8 af[4], bf[2];
    #pragma unroll
    for(int m = 0; m < 4; m++) af[m] = *(const s16x8*)(ap[m] + kk*32);
    #pragma unroll
    for(int n = 0; n < 2; n++) bf[n] = *(const s16x8*)(Bl + (wn*32 + n*16 + l15)*KS + kk*32 + lg*8);
    #pragma unroll
    for(int m = 0; m < 4; m++)
      #pragma unroll
      for(int n = 0; n < 2; n++)
        acc[m][n] = __builtin_amdgcn_mfma_f32_16x16x32_bf16(af[m], bf[n], acc[m][n], 0, 0, 0);
  }
  // epilogue
  #pragma unroll
  for(int n = 0; n < 2; n++){
    int colg = colbase + wn*32 + n*16 + l15;
    float bs = bias[colg];
    #pragma unroll
    for(int m = 0; m < 4; m++){
      long rowg = rowbase + wm*64 + m*16 + lg*4;
      #pragma unroll
      for(int r = 0; r < 4; r++){
        long idx = (rowg + r)*(long)N + colg;
        float v = acc[m][n][r] + bs;
        if(flags & 1) v = 0.5f*v*(1.f + erff(v*0.70710678118f));
        if(flags & 4) v *= 0.17677669529663687f;   // 32^-0.5
        if(resb) v += b2f(resb[idx]);
        if(flags & 8){
          v += resf[idx];
          int rg = (int)(rowg + r);
          int bb = rg >> 14, hw = rg & 16383;
          ((float*)outp)[((long)bb*192 + colg)*16384 + hw] = v;
        } else if(flags & 2){
          ((float*)outp)[idx] = v;
        } else {
          ((unsigned short*)outp)[idx] = f2b(v);
        }
      }
    }
  }
}

// ---------------- Attention ----------------
// 1536 blocks = (win 128) x (h 6) x (qhalf 2), XCD-swizzled so same-window blocks share XCD.
// 4 waves/block, each wave owns 32 q rows. K staged row-PERMUTED in LDS so the QK^T
// output fragment (kpos = lg*8 + mt*4 + r) is directly the PV B-fragment: P stays in regs.
__global__ __launch_bounds__(256) void attn_k(
    const unsigned short* __restrict__ qmat, const unsigned short* __restrict__ kvmat,
    const unsigned short* __restrict__ bt, unsigned short* __restrict__ omat){
  __shared__ unsigned short Kl[192*40];   // permuted rows, stride 40
  __shared__ unsigned short Vl[32*202];   // [d][pos] transposed, stride 202 (conflict-free)
  int tid = threadIdx.x, lane = tid & 63, wv = tid >> 6;
  int l15 = lane & 15, lg = lane >> 4;
  int bid = blockIdx.x;
  int X = bid & 7, j0 = bid >> 3;
  int win = X + 8*(j0 & 15);
  int r12 = j0 >> 4;                  // 0..11
  int h = r12 >> 1, qh = r12 & 1;
  int b = win >> 6, wi = (win >> 3) & 7, wj = win & 7;
  int qbase = qh*128 + wv*32;

  // Q fragments direct from global (pre-scaled by 32^-0.5 in Q GEMM epilogue)
  s16x8 qb[2];
  #pragma unroll
  for(int nt = 0; nt < 2; nt++){
    int q = qbase + nt*16 + l15;
    long tok = (long)b*16384 + (wi*16 + (q>>4))*128 + wj*16 + (q&15);
    qb[nt] = *(const s16x8*)(qmat + tok*192 + h*32 + lg*8);
  }
  float m_run[2] = {-1e30f, -1e30f};
  float l_run[2] = {0.f, 0.f};
  f32x4 oacc[2][2];
  #pragma unroll
  for(int mt=0;mt<2;mt++)
    #pragma unroll
    for(int nt=0;nt<2;nt++) oacc[mt][nt] = (f32x4){0.f,0.f,0.f,0.f};

  for(int ch = 0; ch < 3; ch++){
    __syncthreads();
    // stage K (row-permuted), V (transposed); zero-fill out-of-image
    #pragma unroll
    for(int i = 0; i < 3; i++){
      int u = i*256 + tid; int p = u >> 2, c = u & 3;
      int gp = ch*192 + p; int ii = gp / 24, jc = gp - ii*24;
      int gr = wi*16 - 4 + ii, gc = wj*16 - 4 + jc;
      bool ok = (gr >= 0) && (gr < 128) && (gc >= 0) && (gc < 128);
      s16x8 vk = (s16x8){0,0,0,0,0,0,0,0};
      s16x8 vv = (s16x8){0,0,0,0,0,0,0,0};
      if(ok){
        long tok = (long)b*16384 + gr*128 + gc;
        vk = *(const s16x8*)(kvmat + tok*384 + h*32 + c*8);
        vv = *(const s16x8*)(kvmat + tok*384 + 192 + h*32 + c*8);
      }
      // permutation: kpos_local = lgk*8 + mt*4 + r  ->  srow = mt*16 + lgk*4 + r
      int pl = p & 31;
      int srow = (p & ~31) + ((pl & 4) << 2) + ((pl >> 3) << 2) + (pl & 3);
      *(s16x8*)(Kl + srow*40 + c*8) = vk;
      #pragma unroll
      for(int j2 = 0; j2 < 8; j2++) Vl[(c*8 + j2)*202 + p] = (unsigned short)vv[j2];
    }
    __syncthreads();
    #pragma unroll 1
    for(int kt = 0; kt < 6; kt++){
      int kb = kt*32;
      s16x8 ka[2];
      #pragma unroll
      for(int mt = 0; mt < 2; mt++) ka[mt] = *(const s16x8*)(Kl + (kb + mt*16 + l15)*40 + lg*8);
      f32x4 zf = (f32x4){0.f,0.f,0.f,0.f};
      f32x4 s[2][2];
      #pragma unroll
      for(int mt = 0; mt < 2; mt++)
        #pragma unroll
        for(int nt = 0; nt < 2; nt++)
          s[mt][nt] = __builtin_amdgcn_mfma_f32_16x16x32_bf16(ka[mt], qb[nt], zf, 0, 0, 0);
      // s[mt][nt][r] is logit for kpos = ch*192 + kb + lg*8 + mt*4 + r, q = qbase+nt*16+l15
      int kg4 = ((ch*192 + kb) >> 2) + lg*2;
      #pragma unroll
      for(int mt = 0; mt < 2; mt++)
        #pragma unroll
        for(int nt = 0; nt < 2; nt++){
          int q = qbase + nt*16 + l15;
          s16x4 bv = *(const s16x4*)(bt + (((h*144 + kg4 + mt)*256 + q) << 2));
          #pragma unroll
          for(int r = 0; r < 4; r++) s[mt][nt][r] += b2f((unsigned short)bv[r]);
        }
      // online softmax (exact defer: skip rescale when max unchanged)
      float lm[2];
      #pragma unroll
      for(int nt = 0; nt < 2; nt++){
        float a0 = fmaxf(fmaxf(s[0][nt][0], s[0][nt][1]), fmaxf(s[0][nt][2], s[0][nt][3]));
        float a1 = fmaxf(fmaxf(s[1][nt][0], s[1][nt][1]), fmaxf(s[1][nt][2], s[1][nt][3]));
        float v = fmaxf(a0, a1);
        v = fmaxf(v, __shfl_xor(v, 16));
        v = fmaxf(v, __shfl_xor(v, 32));
        lm[nt] = v;
      }
      if(__any((lm[0] > m_run[0]) || (lm[1] > m_run[1]))){
        #pragma unroll
        for(int nt = 0; nt < 2; nt++){
          float nm = fmaxf(m_run[nt], lm[nt]);
          float fac = __expf(m_run[nt] - nm);
          m_run[nt] = nm;
          l_run[nt] *= fac;
          #pragma unroll
          for(int mt = 0; mt < 2; mt++)
            #pragma unroll
            for(int r = 0; r < 4; r++) oacc[mt][nt][r] *= fac;
        }
      }
      // P = exp(S - m): pack in-register into PV B-fragment (no exchange needed)
      s16x8 pb2[2];
      #pragma unroll
      for(int nt = 0; nt < 2; nt++){
        unsigned int w[4];
        #pragma unroll
        for(int mt = 0; mt < 2; mt++){
          float p0 = __expf(s[mt][nt][0] - m_run[nt]);
          float p1 = __expf(s[mt][nt][1] - m_run[nt]);
          float p2 = __expf(s[mt][nt][2] - m_run[nt]);
          float p3 = __expf(s[mt][nt][3] - m_run[nt]);
          l_run[nt] += (p0 + p1) + (p2 + p3);
          w[mt*2+0] = pk_bf16(p0, p1);
          w[mt*2+1] = pk_bf16(p2, p3);
        }
        pb2[nt] = __builtin_bit_cast(s16x8, w);
      }
      s16x8 va[2];
      #pragma unroll
      for(int mt = 0; mt < 2; mt++) va[mt] = *(const s16x8*)(Vl + (mt*16 + l15)*202 + kb + lg*8);
      #pragma unroll
      for(int mt = 0; mt < 2; mt++)
        #pragma unroll
        for(int nt = 0; nt < 2; nt++)
          oacc[mt][nt] = __builtin_amdgcn_mfma_f32_16x16x32_bf16(va[mt], pb2[nt], oacc[mt][nt], 0, 0, 0);
    }
  }
  // finalize: O^T[d][q] / l
  #pragma unroll
  for(int nt = 0; nt < 2; nt++){
    float l = l_run[nt];
    l += __shfl_xor(l, 16);
    l += __shfl_xor(l, 32);
    float inv = 1.f / l;
    int q = qbase + nt*16 + l15;
    long tok = (long)b*16384 + (wi*16 + (q>>4))*128 + wj*16 + (q&15);
    #pragma unroll
    for(int mt = 0; mt < 2; mt++){
      s16x4 o;
      #pragma unroll
      for(int r = 0; r < 4; r++) o[r] = (short)f2b(oacc[mt][nt][r] * inv);
      *(s16x4*)(omat + tok*192 + h*32 + mt*16 + lg*4) = o;
    }
  }
}

// ---------------- LN2: r2 (f32 token-major) -> n2 bf16 ----------------
__global__ __launch_bounds__(256) void ln2_k(
    const float* __restrict__ in, const float* __restrict__ g,
    const float* __restrict__ be, unsigned short* __restrict__ out){
  __shared__ float t[64][193];
  __shared__ float ps[4][64], pq[4][64];
  __shared__ float mu_s[64], rs_s[64];
  int tid = threadIdx.x;
  long tokbase = (long)blockIdx.x * 64;
  long base = tokbase * 192;
  for(int u = tid; u < 64*192; u += 256){
    int tk = u / 192, ch = u - tk*192;
    t[tk][ch] = in[base + u];
  }
  __syncthreads();
  int tok = tid & 63, cpart = tid >> 6;
  float s = 0.f, q = 0.f;
  #pragma unroll 4
  for(int i = 0; i < 48; i++){ float v = t[tok][cpart*48 + i]; s += v; q += v*v; }
  ps[cpart][tok] = s; pq[cpart][tok] = q;
  __syncthreads();
  if(tid < 64){
    float ss = ps[0][tid]+ps[1][tid]+ps[2][tid]+ps[3][tid];
    float qq = pq[0][tid]+pq[1][tid]+pq[2][tid]+pq[3][tid];
    float mu = ss * (1.f/192.f);
    float var = qq * (1.f/192.f) - mu*mu;
    mu_s[tid] = mu; rs_s[tid] = 1.f/sqrtf(var + 1e-5f);
  }
  __syncthreads();
  for(int u = tid; u < 64*192; u += 256){
    int tk = u / 192, ch = u - tk*192;
    out[base + u] = f2b((t[tk][ch] - mu_s[tk]) * rs_s[tk] * g[ch] + be[ch]);
  }
}

extern "C" void kernel_launch(void* const* d_in, const int* in_sizes, int n_in,
                              void* d_out, int out_size, void* d_ws, size_t ws_size,
                              hipStream_t stream) {
  const float* x     = (const float*)d_in[0];
  const float* depth = (const float*)d_in[1];
  const int*   rpi   = (const int*)d_in[2];
  const float* n1w   = (const float*)d_in[3];
  const float* n1b   = (const float*)d_in[4];
  const float* qkvw  = (const float*)d_in[5];
  const float* qkvb  = (const float*)d_in[6];
  const float* dprjw = (const float*)d_in[7];
  const float* dprjb = (const float*)d_in[8];
  const float* rpb   = (const float*)d_in[9];
  const float* prjw  = (const float*)d_in[10];
  const float* prjb  = (const float*)d_in[11];
  const float* n2w   = (const float*)d_in[12];
  const float* n2b   = (const float*)d_in[13];
  const float* fc1w  = (const float*)d_in[14];
  const float* fc1b  = (const float*)d_in[15];
  const float* fc2w  = (const float*)d_in[16];
  const float* fc2b  = (const float*)d_in[17];

  char* ws = (char*)d_ws;
  unsigned short* xn  = (unsigned short*)(ws + 0);          // 12.6MB (dead after KV gemm)
  unsigned short* dn  = (unsigned short*)(ws + 12582912);   // 12.6MB (dead after Q gemm)
  unsigned short* xf  = (unsigned short*)(ws + 25165824);   // 12.6MB (dead after proj)
  unsigned short* kv  = (unsigned short*)(ws + 37748736);   // 25.2MB (dead after attn)
  unsigned short* h1  = (unsigned short*)(ws + 37748736);   //   overlays kv
  unsigned short* qm  = (unsigned short*)(ws + 62914560);   // 12.6MB (dead after attn)
  float*          r2  = (float*)(ws + 75497472);            // 25.2MB
  unsigned short* om  = (unsigned short*)(ws + 100663296);  // 12.6MB (dead after proj)
  unsigned short* n2  = (unsigned short*)(ws + 100663296);  //   overlays om
  unsigned short* kvw = (unsigned short*)(ws + 113246208);
  unsigned short* dpw = (unsigned short*)(ws + 113393664);
  unsigned short* pjw = (unsigned short*)(ws + 113467392);
  unsigned short* f1w = (unsigned short*)(ws + 113541120);
  unsigned short* f2w = (unsigned short*)(ws + 113688576);
  unsigned short* bt  = (unsigned short*)(ws + 113836032);  // 1769472B -> end 115605504

  prep_w<<<4608, 256, 0, stream>>>(qkvw, dprjw, prjw, fc1w, fc2w, rpi, rpb,
                                   kvw, dpw, pjw, f1w, f2w, bt);
  prep_x<<<512, 256, 0, stream>>>(x, depth, n1w, n1b, xn, xf, dn);
  // KV = LN1(x) @ qkv_w[:,192:576] + b
  gemm2<<<1536, 256, 25600, stream>>>(xn, kvw, qkvb + 192, nullptr, nullptr, kv, 192, 384, 0);
  // Q = (depth @ dproj_w^T + b) * scale   (pre-scaled for attention)
  gemm2<<<768, 256, 25600, stream>>>(dn, dpw, dprjb, nullptr, nullptr, qm, 192, 192, 4);
  attn_k<<<1536, 256, 0, stream>>>(qm, kv, bt, om);
  // r2 = attn_out @ proj_w + b + xf   (f32)
  gemm2<<<768, 256, 25600, stream>>>(om, pjw, prjb, xf, nullptr, r2, 192, 192, 2);
  ln2_k<<<512, 256, 0, stream>>>(r2, n2w, n2b, n2);
  // h1 = gelu(n2 @ fc1_w + b)
  gemm2<<<1536, 256, 25600, stream>>>(n2, f1w, fc1b, nullptr, nullptr, h1, 192, 384, 1);
  // out(NCHW f32) = h1 @ fc2_w + b + r2
  gemm2<<<768, 256, 50176, stream>>>(h1, f2w, fc2b, nullptr, r2, d_out, 384, 192, 8);
}

// Round 4
// 218.852 us; speedup vs baseline: 1.1768x; 1.1602x over previous
//
#include <hip/hip_runtime.h>
#include <math.h>

typedef __attribute__((ext_vector_type(8))) short s16x8;
typedef __attribute__((ext_vector_type(4))) short s16x4;
typedef __attribute__((ext_vector_type(4))) float f32x4;

#define DEV __device__ __forceinline__

DEV float b2f(unsigned short u){ unsigned int x = ((unsigned int)u)<<16u; return __builtin_bit_cast(float,x); }
DEV unsigned short f2b(float f){
  unsigned int x = __builtin_bit_cast(unsigned int,f);
  x += 0x7fffu + ((x>>16)&1u);
  return (unsigned short)(x>>16);
}
DEV unsigned int pk_bf16(float lo, float hi){
  unsigned int r;
  asm("v_cvt_pk_bf16_f32 %0, %1, %2" : "=v"(r) : "v"(lo), "v"(hi));
  return r;
}

// ---------------- prep_all: [0,512) = transpose+LN1, [512,5120) = weights + bias table ----
__global__ __launch_bounds__(256) void prep_all(
    const float* __restrict__ x, const float* __restrict__ depth,
    const float* __restrict__ g, const float* __restrict__ be,
    const float* __restrict__ qkvw, const float* __restrict__ dprojw,
    const float* __restrict__ projw, const float* __restrict__ fc1w,
    const float* __restrict__ fc2w, const int* __restrict__ rpi,
    const float* __restrict__ rpb,
    unsigned short* xn, unsigned short* xf, unsigned short* dn,
    unsigned short* kvw, unsigned short* dpw, unsigned short* pjw,
    unsigned short* f1w, unsigned short* f2w, unsigned short* bt){
  __shared__ float t[64][193];
  __shared__ float ps[4][64], pq[4][64];
  __shared__ float mu_s[64], rs_s[64];
  int tid = threadIdx.x;
  int bid = blockIdx.x;
  if(bid >= 512){
    int i = (bid - 512)*256 + tid;
    if(i < 73728){                       // kvw [384][192] = qkv_w[:,192+n]
      int n = i/192, k = i - n*192;
      kvw[i] = f2b(qkvw[k*576 + 192 + n]);
    } else if(i < 110592){               // dpw: dproj_w already [out][in]
      int j = i - 73728;
      dpw[j] = f2b(dprojw[j]);
    } else if(i < 147456){               // pjw [192][192]
      int j = i - 110592; int n = j/192, k = j - n*192;
      pjw[j] = f2b(projw[k*192 + n]);
    } else if(i < 221184){               // f1w [384][192]
      int j = i - 147456; int n = j/192, k = j - n*192;
      f1w[j] = f2b(fc1w[k*384 + n]);
    } else if(i < 294912){               // f2w [192][384]
      int j = i - 221184; int n = j/384, k = j - n*384;
      f2w[j] = f2b(fc2w[k*192 + n]);
    } else {                             // bias_t [h][k>>2][q][k&3]
      int j = i - 294912;
      int h = j/147456; int rr = j - h*147456;
      int kk = rr >> 8; int q = rr & 255;
      bt[((h*144 + (kk>>2))*256 + q)*4 + (kk&3)] = f2b(rpb[rpi[q*576 + kk]*6 + h]);
    }
    return;
  }
  long tokbase = (long)bid * 64;
  int b = (int)(tokbase >> 14); int hw = (int)(tokbase & 16383);
  const float* xb = x + ((long)b*192)*16384 + hw;
  int tok = tid & 63, cpart = tid >> 6;
  for(int c = cpart; c < 192; c += 4) t[tok][c] = xb[(long)c*16384 + tok];
  __syncthreads();
  float s = 0.f, q = 0.f;
  #pragma unroll 4
  for(int i = 0; i < 48; i++){ float v = t[tok][cpart*48 + i]; s += v; q += v*v; }
  ps[cpart][tok] = s; pq[cpart][tok] = q;
  __syncthreads();
  if(tid < 64){
    float ss = ps[0][tid]+ps[1][tid]+ps[2][tid]+ps[3][tid];
    float qq = pq[0][tid]+pq[1][tid]+pq[2][tid]+pq[3][tid];
    float mu = ss * (1.f/192.f);
    float var = qq * (1.f/192.f) - mu*mu;
    mu_s[tid] = mu; rs_s[tid] = 1.f/sqrtf(var + 1e-5f);
  }
  __syncthreads();
  long obase = tokbase * 192;
  for(int u = tid; u < 64*192; u += 256){
    int tk = u / 192, ch = u - tk*192;
    float v = t[tk][ch];
    xf[obase + u] = f2b(v);
    xn[obase + u] = f2b((v - mu_s[tk]) * rs_s[tk] * g[ch] + be[ch]);
  }
  __syncthreads();
  const float* db = depth + ((long)b*192)*16384 + hw;
  for(int c = cpart; c < 192; c += 4) t[tok][c] = db[(long)c*16384 + tok];
  __syncthreads();
  for(int u = tid; u < 64*192; u += 256){
    int tk = u / 192, ch = u - tk*192;
    dn[obase + u] = f2b(t[tk][ch]);
  }
}

// ---------------- GEMM body: tile 128x64, W in LDS once, A direct from global ----------------
// flags: 1=gelu, 4=*attn_scale, 8=fc2 (f32 NCHW out via LDS transpose, +resf)
DEV void gemm_body(const unsigned short* __restrict__ A, const unsigned short* __restrict__ W,
                   const float* __restrict__ bias, const float* __restrict__ resf,
                   void* outp, int K, int N, int flags, int bid,
                   unsigned short* Bl, int tid){
  int lane = tid & 63, wv = tid >> 6;
  int wm = wv >> 1, wn = wv & 1, l15 = lane & 15, lg = lane >> 4;
  int X = bid & 7, j = bid >> 3;
  int mb = X + 8*(j & 31);
  int nb = j >> 5;
  long rowbase = (long)mb * 128;
  int colbase = nb * 64;
  int KS = K + 8, K8 = K >> 3;
  int nv = 64 * K8;
  for(int u = tid; u < nv; u += 256){
    int row = u / K8, c = u - row*K8;
    *(s16x8*)(Bl + row*KS + c*8) = *(const s16x8*)(W + (long)(colbase + row)*K + c*8);
  }
  __syncthreads();
  const unsigned short* ap[4];
  #pragma unroll
  for(int m = 0; m < 4; m++) ap[m] = A + (rowbase + wm*64 + m*16 + l15)*(long)K + lg*8;
  f32x4 acc[4][2];
  #pragma unroll
  for(int m=0;m<4;m++)
    #pragma unroll
    for(int n=0;n<2;n++) acc[m][n] = (f32x4){0.f,0.f,0.f,0.f};
  int nkk = K >> 5;
  #pragma unroll 3
  for(int kk = 0; kk < nkk; kk++){
    s16x8 af[4], bf[2];
    #pragma unroll
    for(int m = 0; m < 4; m++) af[m] = *(const s16x8*)(ap[m] + kk*32);
    #pragma unroll
    for(int n = 0; n < 2; n++) bf[n] = *(const s16x8*)(Bl + (wn*32 + n*16 + l15)*KS + kk*32 + lg*8);
    #pragma unroll
    for(int m = 0; m < 4; m++)
      #pragma unroll
      for(int n = 0; n < 2; n++)
        acc[m][n] = __builtin_amdgcn_mfma_f32_16x16x32_bf16(af[m], bf[n], acc[m][n], 0, 0, 0);
  }
  if(flags & 8){
    // fc2: v = acc + bias + resf; transpose via LDS; coalesced NCHW f32 store
    float vloc[2][4][4];
    #pragma unroll
    for(int n = 0; n < 2; n++){
      int colg = colbase + wn*32 + n*16 + l15;
      float bs = bias[colg];
      #pragma unroll
      for(int m = 0; m < 4; m++){
        long rowg = rowbase + wm*64 + m*16 + lg*4;
        #pragma unroll
        for(int r = 0; r < 4; r++){
          long idx = (rowg + r)*(long)N + colg;
          vloc[n][m][r] = acc[m][n][r] + bs + resf[idx];
        }
      }
    }
    __syncthreads();
    float* T = (float*)Bl;      // [64 ch][132 tok] = 33792B <= 50176B
    #pragma unroll
    for(int n = 0; n < 2; n++){
      int chl = wn*32 + n*16 + l15;
      #pragma unroll
      for(int m = 0; m < 4; m++){
        int tl = wm*64 + m*16 + lg*4;
        #pragma unroll
        for(int r = 0; r < 4; r++) T[chl*132 + tl + r] = vloc[n][m][r];
      }
    }
    __syncthreads();
    int bb = (int)(rowbase >> 14), hw0 = (int)(rowbase & 16383);
    float* op = (float*)outp;
    for(int u = tid; u < 8192; u += 256){
      int chn = u >> 7, t2 = u & 127;
      op[((long)bb*192 + colbase + chn)*16384 + hw0 + t2] = T[chn*132 + t2];
    }
    return;
  }
  #pragma unroll
  for(int n = 0; n < 2; n++){
    int colg = colbase + wn*32 + n*16 + l15;
    float bs = bias[colg];
    #pragma unroll
    for(int m = 0; m < 4; m++){
      long rowg = rowbase + wm*64 + m*16 + lg*4;
      #pragma unroll
      for(int r = 0; r < 4; r++){
        long idx = (rowg + r)*(long)N + colg;
        float v = acc[m][n][r] + bs;
        if(flags & 1) v = 0.5f*v*(1.f + erff(v*0.70710678118f));
        if(flags & 4) v *= 0.17677669529663687f;   // 32^-0.5
        ((unsigned short*)outp)[idx] = f2b(v);
      }
    }
  }
}

// KV gemm (blocks 0..1535) + Q gemm (1536..2303) in one dispatch
__global__ __launch_bounds__(256) void gemm_kvq(
    const unsigned short* __restrict__ xn, const unsigned short* __restrict__ dn,
    const unsigned short* __restrict__ kvw, const unsigned short* __restrict__ dpw,
    const float* __restrict__ kvb, const float* __restrict__ dpb,
    unsigned short* kv, unsigned short* qm){
  extern __shared__ unsigned short Bl[];
  int bid = blockIdx.x, tid = threadIdx.x;
  if(bid < 1536) gemm_body(xn, kvw, kvb, nullptr, kv, 192, 384, 0, bid, Bl, tid);
  else           gemm_body(dn, dpw, dpb, nullptr, qm, 192, 192, 4, bid - 1536, Bl, tid);
}

__global__ __launch_bounds__(256) void gemm2(
    const unsigned short* __restrict__ A, const unsigned short* __restrict__ W,
    const float* __restrict__ bias, const float* __restrict__ resf,
    void* outp, int K, int N, int flags){
  extern __shared__ unsigned short Bl[];
  gemm_body(A, W, bias, resf, outp, K, N, flags, blockIdx.x, Bl, threadIdx.x);
}

// ---------------- Attention ----------------
DEV void attn_issue(int ch, int tid, int b, int wi, int wj, int h,
                    const unsigned short* __restrict__ kvmat,
                    s16x8* pk_, s16x8* pv_){
  #pragma unroll
  for(int i = 0; i < 3; i++){
    int u = i*256 + tid; int p = u >> 2, c = u & 3;
    int gp = ch*192 + p; int ii = gp / 24, jc = gp - ii*24;
    int gr = wi*16 - 4 + ii, gc = wj*16 - 4 + jc;
    bool ok = (gr >= 0) && (gr < 128) && (gc >= 0) && (gc < 128);
    s16x8 z = (s16x8){0,0,0,0,0,0,0,0};
    pk_[i] = z; pv_[i] = z;
    if(ok){
      long tok = (long)b*16384 + gr*128 + gc;
      pk_[i] = *(const s16x8*)(kvmat + tok*384 + h*32 + c*8);
      pv_[i] = *(const s16x8*)(kvmat + tok*384 + 192 + h*32 + c*8);
    }
  }
}

// 1536 blocks = (win 128) x (h 6) x (qhalf 2), XCD-swizzled. 4 waves x 32 q rows.
// K staged row-permuted so QK^T output fragment == PV B-fragment (P stays in regs).
// 64-kv softmax steps + T14 prefetch of next chunk into registers.
__global__ __launch_bounds__(256) void attn_k(
    const unsigned short* __restrict__ qmat, const unsigned short* __restrict__ kvmat,
    const unsigned short* __restrict__ bt, unsigned short* __restrict__ omat){
  __shared__ unsigned short Kl[192*40];   // permuted rows, stride 40
  __shared__ unsigned short Vl[32*202];   // [d][pos] transposed, stride 202
  int tid = threadIdx.x, lane = tid & 63, wv = tid >> 6;
  int l15 = lane & 15, lg = lane >> 4;
  int bid = blockIdx.x;
  int X = bid & 7, j0 = bid >> 3;
  int win = X + 8*(j0 & 15);
  int r12 = j0 >> 4;
  int h = r12 >> 1, qh = r12 & 1;
  int b = win >> 6, wi = (win >> 3) & 7, wj = win & 7;
  int qbase = qh*128 + wv*32;

  s16x8 qb[2];
  #pragma unroll
  for(int nt = 0; nt < 2; nt++){
    int q = qbase + nt*16 + l15;
    long tok = (long)b*16384 + (wi*16 + (q>>4))*128 + wj*16 + (q&15);
    qb[nt] = *(const s16x8*)(qmat + tok*192 + h*32 + lg*8);
  }
  float m_run[2] = {-1e30f, -1e30f};
  float l_run[2] = {0.f, 0.f};
  f32x4 oacc[2][2];
  #pragma unroll
  for(int mtd=0;mtd<2;mtd++)
    #pragma unroll
    for(int nt=0;nt<2;nt++) oacc[mtd][nt] = (f32x4){0.f,0.f,0.f,0.f};

  s16x8 pk_[3], pv_[3];
  attn_issue(0, tid, b, wi, wj, h, kvmat, pk_, pv_);

  for(int ch = 0; ch < 3; ch++){
    __syncthreads();
    #pragma unroll
    for(int i = 0; i < 3; i++){
      int u = i*256 + tid; int p = u >> 2, c = u & 3;
      int pl = p & 31;
      int srow = (p & ~31) + ((pl & 4) << 2) + ((pl >> 3) << 2) + (pl & 3);
      *(s16x8*)(Kl + srow*40 + c*8) = pk_[i];
      #pragma unroll
      for(int j2 = 0; j2 < 8; j2++) Vl[(c*8 + j2)*202 + p] = (unsigned short)pv_[i][j2];
    }
    __syncthreads();
    if(ch < 2) attn_issue(ch+1, tid, b, wi, wj, h, kvmat, pk_, pv_);
    #pragma unroll
    for(int ktt = 0; ktt < 3; ktt++){
      int kb = ktt*64;
      s16x8 ka[4];
      #pragma unroll
      for(int mt = 0; mt < 4; mt++) ka[mt] = *(const s16x8*)(Kl + (kb + mt*16 + l15)*40 + lg*8);
      f32x4 zf = (f32x4){0.f,0.f,0.f,0.f};
      f32x4 s[4][2];
      #pragma unroll
      for(int mt = 0; mt < 4; mt++)
        #pragma unroll
        for(int nt = 0; nt < 2; nt++)
          s[mt][nt] = __builtin_amdgcn_mfma_f32_16x16x32_bf16(ka[mt], qb[nt], zf, 0, 0, 0);
      // bias: kpos = ch*192 + kb + (mt>>1)*32 + lg*8 + (mt&1)*4 + r
      int base4 = (ch*192 + kb) >> 2;
      #pragma unroll
      for(int mt = 0; mt < 4; mt++)
        #pragma unroll
        for(int nt = 0; nt < 2; nt++){
          int q = qbase + nt*16 + l15;
          int k4 = base4 + (mt>>1)*8 + lg*2 + (mt&1);
          s16x4 bv = *(const s16x4*)(bt + (((h*144 + k4)*256 + q) << 2));
          #pragma unroll
          for(int r = 0; r < 4; r++) s[mt][nt][r] += b2f((unsigned short)bv[r]);
        }
      // softmax over 64 kv
      float lm[2];
      #pragma unroll
      for(int nt = 0; nt < 2; nt++){
        float a0 = fmaxf(fmaxf(s[0][nt][0], s[0][nt][1]), fmaxf(s[0][nt][2], s[0][nt][3]));
        float a1 = fmaxf(fmaxf(s[1][nt][0], s[1][nt][1]), fmaxf(s[1][nt][2], s[1][nt][3]));
        float a2 = fmaxf(fmaxf(s[2][nt][0], s[2][nt][1]), fmaxf(s[2][nt][2], s[2][nt][3]));
        float a3 = fmaxf(fmaxf(s[3][nt][0], s[3][nt][1]), fmaxf(s[3][nt][2], s[3][nt][3]));
        float v = fmaxf(fmaxf(a0, a1), fmaxf(a2, a3));
        v = fmaxf(v, __shfl_xor(v, 16));
        v = fmaxf(v, __shfl_xor(v, 32));
        lm[nt] = v;
      }
      if(__any((lm[0] > m_run[0]) || (lm[1] > m_run[1]))){
        #pragma unroll
        for(int nt = 0; nt < 2; nt++){
          float nm = fmaxf(m_run[nt], lm[nt]);
          float fac = __expf(m_run[nt] - nm);
          m_run[nt] = nm;
          l_run[nt] *= fac;
          #pragma unroll
          for(int mtd = 0; mtd < 2; mtd++)
            #pragma unroll
            for(int r = 0; r < 4; r++) oacc[mtd][nt][r] *= fac;
        }
      }
      // P = exp(S-m), packed directly into PV B-fragments (2 k-groups of 32)
      s16x8 pb[2][2];
      #pragma unroll
      for(int nt = 0; nt < 2; nt++){
        #pragma unroll
        for(int gk = 0; gk < 2; gk++){
          float p0 = __expf(s[gk*2+0][nt][0] - m_run[nt]);
          float p1 = __expf(s[gk*2+0][nt][1] - m_run[nt]);
          float p2 = __expf(s[gk*2+0][nt][2] - m_run[nt]);
          float p3 = __expf(s[gk*2+0][nt][3] - m_run[nt]);
          float p4 = __expf(s[gk*2+1][nt][0] - m_run[nt]);
          float p5 = __expf(s[gk*2+1][nt][1] - m_run[nt]);
          float p6 = __expf(s[gk*2+1][nt][2] - m_run[nt]);
          float p7 = __expf(s[gk*2+1][nt][3] - m_run[nt]);
          l_run[nt] += ((p0+p1)+(p2+p3)) + ((p4+p5)+(p6+p7));
          unsigned int w[4];
          w[0] = pk_bf16(p0, p1); w[1] = pk_bf16(p2, p3);
          w[2] = pk_bf16(p4, p5); w[3] = pk_bf16(p6, p7);
          pb[gk][nt] = __builtin_bit_cast(s16x8, w);
        }
      }
      s16x8 va[2][2];
      #pragma unroll
      for(int mtd = 0; mtd < 2; mtd++)
        #pragma unroll
        for(int gk = 0; gk < 2; gk++)
          va[mtd][gk] = *(const s16x8*)(Vl + (mtd*16 + l15)*202 + kb + gk*32 + lg*8);
      #pragma unroll
      for(int mtd = 0; mtd < 2; mtd++)
        #pragma unroll
        for(int nt = 0; nt < 2; nt++){
          oacc[mtd][nt] = __builtin_amdgcn_mfma_f32_16x16x32_bf16(va[mtd][0], pb[0][nt], oacc[mtd][nt], 0, 0, 0);
          oacc[mtd][nt] = __builtin_amdgcn_mfma_f32_16x16x32_bf16(va[mtd][1], pb[1][nt], oacc[mtd][nt], 0, 0, 0);
        }
    }
  }
  #pragma unroll
  for(int nt = 0; nt < 2; nt++){
    float l = l_run[nt];
    l += __shfl_xor(l, 16);
    l += __shfl_xor(l, 32);
    float inv = 1.f / l;
    int q = qbase + nt*16 + l15;
    long tok = (long)b*16384 + (wi*16 + (q>>4))*128 + wj*16 + (q&15);
    #pragma unroll
    for(int mtd = 0; mtd < 2; mtd++){
      s16x4 o;
      #pragma unroll
      for(int r = 0; r < 4; r++) o[r] = (short)f2b(oacc[mtd][nt][r] * inv);
      *(s16x4*)(omat + tok*192 + h*32 + mtd*16 + lg*4) = o;
    }
  }
}

// ---------------- proj + residual + LN2 fused: 64 rows x full 192 cols per block ----------------
__global__ __launch_bounds__(256) void proj_ln(
    const unsigned short* __restrict__ A, const unsigned short* __restrict__ W,
    const float* __restrict__ bias, const unsigned short* __restrict__ resb,
    const float* __restrict__ g2, const float* __restrict__ b2,
    float* __restrict__ r2, unsigned short* __restrict__ n2){
  extern __shared__ char smem[];
  unsigned short* Bl = (unsigned short*)smem;             // [192][200] = 76800B
  float* ps = (float*)(smem + 76800);                     // [4][64]
  float* pq = (float*)(smem + 77824);                     // [4][64]
  float* mu_s = (float*)(smem + 78848);                   // [64]
  float* rs_s = (float*)(smem + 79104);                   // [64] -> 79360B total
  int tid = threadIdx.x, lane = tid & 63, wv = tid >> 6;
  int l15 = lane & 15, lg = lane >> 4;
  long rowbase = (long)blockIdx.x * 64;
  for(int u = tid; u < 192*24; u += 256){
    int row = u / 24, c = u - row*24;
    *(s16x8*)(Bl + row*200 + c*8) = *(const s16x8*)(W + row*192 + c*8);
  }
  __syncthreads();
  const unsigned short* ap[4];
  #pragma unroll
  for(int m = 0; m < 4; m++) ap[m] = A + (rowbase + m*16 + l15)*192 + lg*8;
  f32x4 acc[4][3];
  #pragma unroll
  for(int m=0;m<4;m++)
    #pragma unroll
    for(int n=0;n<3;n++) acc[m][n] = (f32x4){0.f,0.f,0.f,0.f};
  #pragma unroll 3
  for(int kk = 0; kk < 6; kk++){
    s16x8 af[4], bf[3];
    #pragma unroll
    for(int m = 0; m < 4; m++) af[m] = *(const s16x8*)(ap[m] + kk*32);
    #pragma unroll
    for(int n = 0; n < 3; n++) bf[n] = *(const s16x8*)(Bl + (wv*48 + n*16 + l15)*200 + kk*32 + lg*8);
    #pragma unroll
    for(int m = 0; m < 4; m++)
      #pragma unroll
      for(int n = 0; n < 3; n++)
        acc[m][n] = __builtin_amdgcn_mfma_f32_16x16x32_bf16(af[m], bf[n], acc[m][n], 0, 0, 0);
  }
  // v = acc + bias + xf ; write r2 f32 ; accumulate row partial sums
  float val[4][3][4];
  float ts[4][4], tq[4][4];
  #pragma unroll
  for(int m=0;m<4;m++)
    #pragma unroll
    for(int r=0;r<4;r++){ ts[m][r]=0.f; tq[m][r]=0.f; }
  #pragma unroll
  for(int n = 0; n < 3; n++){
    int colg = wv*48 + n*16 + l15;
    float bs = bias[colg];
    #pragma unroll
    for(int m = 0; m < 4; m++){
      long rowg = rowbase + m*16 + lg*4;
      #pragma unroll
      for(int r = 0; r < 4; r++){
        long idx = (rowg + r)*192 + colg;
        float v = acc[m][n][r] + bs + b2f(resb[idx]);
        val[m][n][r] = v;
        ts[m][r] += v; tq[m][r] += v*v;
        r2[idx] = v;
      }
    }
  }
  #pragma unroll
  for(int m = 0; m < 4; m++)
    #pragma unroll
    for(int r = 0; r < 4; r++){
      float s1 = ts[m][r], q1 = tq[m][r];
      #pragma unroll
      for(int off = 1; off < 16; off <<= 1){
        s1 += __shfl_xor(s1, off);
        q1 += __shfl_xor(q1, off);
      }
      if(l15 == 0){
        int row = m*16 + lg*4 + r;
        ps[wv*64 + row] = s1; pq[wv*64 + row] = q1;
      }
    }
  __syncthreads();
  if(tid < 64){
    float ss = ps[tid] + ps[64+tid] + ps[128+tid] + ps[192+tid];
    float qq = pq[tid] + pq[64+tid] + pq[128+tid] + pq[192+tid];
    float mu = ss * (1.f/192.f);
    float var = qq * (1.f/192.f) - mu*mu;
    mu_s[tid] = mu; rs_s[tid] = 1.f/sqrtf(var + 1e-5f);
  }
  __syncthreads();
  #pragma unroll
  for(int n = 0; n < 3; n++){
    int colg = wv*48 + n*16 + l15;
    float gg = g2[colg], bb = b2[colg];
    #pragma unroll
    for(int m = 0; m < 4; m++){
      long rowg = rowbase + m*16 + lg*4;
      #pragma unroll
      for(int r = 0; r < 4; r++){
        int row = m*16 + lg*4 + r;
        long idx = (rowg + r)*192 + colg;
        n2[idx] = f2b((val[m][n][r] - mu_s[row]) * rs_s[row] * gg + bb);
      }
    }
  }
}

extern "C" void kernel_launch(void* const* d_in, const int* in_sizes, int n_in,
                              void* d_out, int out_size, void* d_ws, size_t ws_size,
                              hipStream_t stream) {
  const float* x     = (const float*)d_in[0];
  const float* depth = (const float*)d_in[1];
  const int*   rpi   = (const int*)d_in[2];
  const float* n1w   = (const float*)d_in[3];
  const float* n1b   = (const float*)d_in[4];
  const float* qkvw  = (const float*)d_in[5];
  const float* qkvb  = (const float*)d_in[6];
  const float* dprjw = (const float*)d_in[7];
  const float* dprjb = (const float*)d_in[8];
  const float* rpb   = (const float*)d_in[9];
  const float* prjw  = (const float*)d_in[10];
  const float* prjb  = (const float*)d_in[11];
  const float* n2w   = (const float*)d_in[12];
  const float* n2b   = (const float*)d_in[13];
  const float* fc1w  = (const float*)d_in[14];
  const float* fc1b  = (const float*)d_in[15];
  const float* fc2w  = (const float*)d_in[16];
  const float* fc2b  = (const float*)d_in[17];

  char* ws = (char*)d_ws;
  unsigned short* xn  = (unsigned short*)(ws + 0);          // 12.6MB (dead after KV gemm)
  unsigned short* dn  = (unsigned short*)(ws + 12582912);   // 12.6MB (dead after Q gemm)
  unsigned short* xf  = (unsigned short*)(ws + 25165824);   // 12.6MB (dead after proj_ln)
  unsigned short* kv  = (unsigned short*)(ws + 37748736);   // 25.2MB (dead after attn)
  unsigned short* h1  = (unsigned short*)(ws + 37748736);   //   overlays kv
  unsigned short* qm  = (unsigned short*)(ws + 62914560);   // 12.6MB (dead after attn)
  float*          r2  = (float*)(ws + 75497472);            // 25.2MB
  unsigned short* om  = (unsigned short*)(ws + 100663296);  // 12.6MB (dead after proj_ln)
  unsigned short* n2  = (unsigned short*)(ws + 100663296);  //   overlays om (safe: barriers)
  unsigned short* kvw = (unsigned short*)(ws + 113246208);
  unsigned short* dpw = (unsigned short*)(ws + 113393664);
  unsigned short* pjw = (unsigned short*)(ws + 113467392);
  unsigned short* f1w = (unsigned short*)(ws + 113541120);
  unsigned short* f2w = (unsigned short*)(ws + 113688576);
  unsigned short* bt  = (unsigned short*)(ws + 113836032);  // 1769472B -> end 115605504

  prep_all<<<5120, 256, 0, stream>>>(x, depth, n1w, n1b, qkvw, dprjw, prjw, fc1w, fc2w,
                                     rpi, rpb, xn, xf, dn, kvw, dpw, pjw, f1w, f2w, bt);
  gemm_kvq<<<2304, 256, 25600, stream>>>(xn, dn, kvw, dpw, qkvb + 192, dprjb, kv, qm);
  attn_k<<<1536, 256, 0, stream>>>(qm, kv, bt, om);
  proj_ln<<<512, 256, 79360, stream>>>(om, pjw, prjb, xf, n2w, n2b, r2, n2);
  gemm2<<<1536, 256, 25600, stream>>>(n2, f1w, fc1b, nullptr, h1, 192, 384, 1);
  gemm2<<<768, 256, 50176, stream>>>(h1, f2w, fc2b, r2, d_out, 384, 192, 8);
}

// Round 5
// 207.356 us; speedup vs baseline: 1.2421x; 1.0554x over previous
//
#include <hip/hip_runtime.h>
#include <math.h>

typedef __attribute__((ext_vector_type(8))) short s16x8;
typedef __attribute__((ext_vector_type(4))) short s16x4;
typedef __attribute__((ext_vector_type(4))) float f32x4;

#define DEV __device__ __forceinline__

DEV float b2f(unsigned short u){ unsigned int x = ((unsigned int)u)<<16u; return __builtin_bit_cast(float,x); }
DEV unsigned short f2b(float f){
  unsigned int x = __builtin_bit_cast(unsigned int,f);
  x += 0x7fffu + ((x>>16)&1u);
  return (unsigned short)(x>>16);
}
DEV unsigned int pk_bf16(float lo, float hi){
  unsigned int r;
  asm("v_cvt_pk_bf16_f32 %0, %1, %2" : "=v"(r) : "v"(lo), "v"(hi));
  return r;
}
DEV float ex2(float x){  // 2^x, native
  float r;
  asm("v_exp_f32 %0, %1" : "=v"(r) : "v"(x));
  return r;
}
#define LOG2E 1.4426950408889634f

// ---------------- prep_all: [0,512) = transpose+LN1, [512,5120) = weights + bias table ----
__global__ __launch_bounds__(256) void prep_all(
    const float* __restrict__ x, const float* __restrict__ depth,
    const float* __restrict__ g, const float* __restrict__ be,
    const float* __restrict__ qkvw, const float* __restrict__ dprojw,
    const float* __restrict__ projw, const float* __restrict__ fc1w,
    const float* __restrict__ fc2w, const int* __restrict__ rpi,
    const float* __restrict__ rpb,
    unsigned short* xn, unsigned short* xf, unsigned short* dn,
    unsigned short* kvw, unsigned short* dpw, unsigned short* pjw,
    unsigned short* f1w, unsigned short* f2w, unsigned short* bt){
  __shared__ float t[64][193];
  __shared__ float ps[4][64], pq[4][64];
  __shared__ float mu_s[64], rs_s[64];
  int tid = threadIdx.x;
  int bid = blockIdx.x;
  if(bid >= 512){
    int i = (bid - 512)*256 + tid;
    if(i < 73728){                       // kvw [384][192] = qkv_w[:,192+n]
      int n = i/192, k = i - n*192;
      kvw[i] = f2b(qkvw[k*576 + 192 + n]);
    } else if(i < 110592){               // dpw: dproj_w already [out][in]
      int j = i - 73728;
      dpw[j] = f2b(dprojw[j]);
    } else if(i < 147456){               // pjw [192][192]
      int j = i - 110592; int n = j/192, k = j - n*192;
      pjw[j] = f2b(projw[k*192 + n]);
    } else if(i < 221184){               // f1w [384][192]
      int j = i - 147456; int n = j/192, k = j - n*192;
      f1w[j] = f2b(fc1w[k*384 + n]);
    } else if(i < 294912){               // f2w [192][384]
      int j = i - 221184; int n = j/384, k = j - n*384;
      f2w[j] = f2b(fc2w[k*192 + n]);
    } else {                             // bias_t [h][step18][lg4][q256][8], pre-multiplied by log2e
      int j = i - 294912;
      int h = j/147456; int rr = j - h*147456;
      int kk = rr >> 8; int q = rr & 255;
      int step = kk >> 5, within = kk & 31;
      int lg = within >> 3, p4r = within & 7;
      bt[h*147456 + step*8192 + lg*2048 + q*8 + p4r] =
          f2b(rpb[rpi[q*576 + kk]*6 + h] * LOG2E);
    }
    return;
  }
  long tokbase = (long)bid * 64;
  int b = (int)(tokbase >> 14); int hw = (int)(tokbase & 16383);
  const float* xb = x + ((long)b*192)*16384 + hw;
  int tok = tid & 63, cpart = tid >> 6;
  for(int c = cpart; c < 192; c += 4) t[tok][c] = xb[(long)c*16384 + tok];
  __syncthreads();
  float s = 0.f, q = 0.f;
  #pragma unroll 4
  for(int i = 0; i < 48; i++){ float v = t[tok][cpart*48 + i]; s += v; q += v*v; }
  ps[cpart][tok] = s; pq[cpart][tok] = q;
  __syncthreads();
  if(tid < 64){
    float ss = ps[0][tid]+ps[1][tid]+ps[2][tid]+ps[3][tid];
    float qq = pq[0][tid]+pq[1][tid]+pq[2][tid]+pq[3][tid];
    float mu = ss * (1.f/192.f);
    float var = qq * (1.f/192.f) - mu*mu;
    mu_s[tid] = mu; rs_s[tid] = 1.f/sqrtf(var + 1e-5f);
  }
  __syncthreads();
  long obase = tokbase * 192;
  for(int u = tid; u < 64*192; u += 256){
    int tk = u / 192, ch = u - tk*192;
    float v = t[tk][ch];
    xf[obase + u] = f2b(v);
    xn[obase + u] = f2b((v - mu_s[tk]) * rs_s[tk] * g[ch] + be[ch]);
  }
  __syncthreads();
  const float* db = depth + ((long)b*192)*16384 + hw;
  for(int c = cpart; c < 192; c += 4) t[tok][c] = db[(long)c*16384 + tok];
  __syncthreads();
  for(int u = tid; u < 64*192; u += 256){
    int tk = u / 192, ch = u - tk*192;
    dn[obase + u] = f2b(t[tk][ch]);
  }
}

// ---------------- GEMM body: tile 128x64, W in LDS once, A direct from global ----------------
// flags: 1=gelu, 4=*(attn_scale*log2e), 8=fc2 (f32 NCHW out via LDS transpose, +resf)
DEV void gemm_body(const unsigned short* __restrict__ A, const unsigned short* __restrict__ W,
                   const float* __restrict__ bias, const float* __restrict__ resf,
                   void* outp, int K, int N, int flags, int bid,
                   unsigned short* Bl, int tid){
  int lane = tid & 63, wv = tid >> 6;
  int wm = wv >> 1, wn = wv & 1, l15 = lane & 15, lg = lane >> 4;
  int X = bid & 7, j = bid >> 3;
  int mb = X + 8*(j & 31);
  int nb = j >> 5;
  long rowbase = (long)mb * 128;
  int colbase = nb * 64;
  int KS = K + 8, K8 = K >> 3;
  int nv = 64 * K8;
  for(int u = tid; u < nv; u += 256){
    int row = u / K8, c = u - row*K8;
    *(s16x8*)(Bl + row*KS + c*8) = *(const s16x8*)(W + (long)(colbase + row)*K + c*8);
  }
  __syncthreads();
  const unsigned short* ap[4];
  #pragma unroll
  for(int m = 0; m < 4; m++) ap[m] = A + (rowbase + wm*64 + m*16 + l15)*(long)K + lg*8;
  f32x4 acc[4][2];
  #pragma unroll
  for(int m=0;m<4;m++)
    #pragma unroll
    for(int n=0;n<2;n++) acc[m][n] = (f32x4){0.f,0.f,0.f,0.f};
  int nkk = K >> 5;
  #pragma unroll 3
  for(int kk = 0; kk < nkk; kk++){
    s16x8 af[4], bf[2];
    #pragma unroll
    for(int m = 0; m < 4; m++) af[m] = *(const s16x8*)(ap[m] + kk*32);
    #pragma unroll
    for(int n = 0; n < 2; n++) bf[n] = *(const s16x8*)(Bl + (wn*32 + n*16 + l15)*KS + kk*32 + lg*8);
    #pragma unroll
    for(int m = 0; m < 4; m++)
      #pragma unroll
      for(int n = 0; n < 2; n++)
        acc[m][n] = __builtin_amdgcn_mfma_f32_16x16x32_bf16(af[m], bf[n], acc[m][n], 0, 0, 0);
  }
  if(flags & 8){
    // fc2: v = acc + bias + resf; transpose via LDS; coalesced NCHW f32 store
    float vloc[2][4][4];
    #pragma unroll
    for(int n = 0; n < 2; n++){
      int colg = colbase + wn*32 + n*16 + l15;
      float bs = bias[colg];
      #pragma unroll
      for(int m = 0; m < 4; m++){
        long rowg = rowbase + wm*64 + m*16 + lg*4;
        #pragma unroll
        for(int r = 0; r < 4; r++){
          long idx = (rowg + r)*(long)N + colg;
          vloc[n][m][r] = acc[m][n][r] + bs + resf[idx];
        }
      }
    }
    __syncthreads();
    float* T = (float*)Bl;      // [64 ch][132 tok] = 33792B <= 50176B
    #pragma unroll
    for(int n = 0; n < 2; n++){
      int chl = wn*32 + n*16 + l15;
      #pragma unroll
      for(int m = 0; m < 4; m++){
        int tl = wm*64 + m*16 + lg*4;
        #pragma unroll
        for(int r = 0; r < 4; r++) T[chl*132 + tl + r] = vloc[n][m][r];
      }
    }
    __syncthreads();
    int bb = (int)(rowbase >> 14), hw0 = (int)(rowbase & 16383);
    float* op = (float*)outp;
    for(int u = tid; u < 8192; u += 256){
      int chn = u >> 7, t2 = u & 127;
      op[((long)bb*192 + colbase + chn)*16384 + hw0 + t2] = T[chn*132 + t2];
    }
    return;
  }
  #pragma unroll
  for(int n = 0; n < 2; n++){
    int colg = colbase + wn*32 + n*16 + l15;
    float bs = bias[colg];
    #pragma unroll
    for(int m = 0; m < 4; m++){
      long rowg = rowbase + wm*64 + m*16 + lg*4;
      #pragma unroll
      for(int r = 0; r < 4; r++){
        long idx = (rowg + r)*(long)N + colg;
        float v = acc[m][n][r] + bs;
        if(flags & 1) v = 0.5f*v*(1.f + erff(v*0.70710678118f));
        if(flags & 4) v *= (0.17677669529663687f * LOG2E);   // 32^-0.5 * log2e
        ((unsigned short*)outp)[idx] = f2b(v);
      }
    }
  }
}

// KV gemm (blocks 0..1535) + Q gemm (1536..2303) in one dispatch
__global__ __launch_bounds__(256) void gemm_kvq(
    const unsigned short* __restrict__ xn, const unsigned short* __restrict__ dn,
    const unsigned short* __restrict__ kvw, const unsigned short* __restrict__ dpw,
    const float* __restrict__ kvb, const float* __restrict__ dpb,
    unsigned short* kv, unsigned short* qm){
  extern __shared__ unsigned short Bl[];
  int bid = blockIdx.x, tid = threadIdx.x;
  if(bid < 1536) gemm_body(xn, kvw, kvb, nullptr, kv, 192, 384, 0, bid, Bl, tid);
  else           gemm_body(dn, dpw, dpb, nullptr, qm, 192, 192, 4, bid - 1536, Bl, tid);
}

__global__ __launch_bounds__(256) void gemm2(
    const unsigned short* __restrict__ A, const unsigned short* __restrict__ W,
    const float* __restrict__ bias, const float* __restrict__ resf,
    void* outp, int K, int N, int flags){
  extern __shared__ unsigned short Bl[];
  gemm_body(A, W, bias, resf, outp, K, N, flags, blockIdx.x, Bl, threadIdx.x);
}

// ---------------- Attention ----------------
// 768 blocks = (win 128) x (h 6), XCD-swizzled. 8 waves x 32 q rows = 256 q.
// K staged row-permuted so QK^T output fragment == PV B-fragment (P stays in regs).
// 32-wide kv steps; logits in log2 domain (Q pre-scaled, bias pre-scaled by log2e).
__global__ __launch_bounds__(512, 6) void attn_k(
    const unsigned short* __restrict__ qmat, const unsigned short* __restrict__ kvmat,
    const unsigned short* __restrict__ bt, unsigned short* __restrict__ omat){
  __shared__ unsigned short Kl[192*40];   // permuted rows, stride 40
  __shared__ unsigned short Vl[32*202];   // [d][pos] transposed, stride 202
  int tid = threadIdx.x, lane = tid & 63, wv = tid >> 6;
  int l15 = lane & 15, lg = lane >> 4;
  int bid = blockIdx.x;
  int X = bid & 7, j0 = bid >> 3;
  int win = X + 8*(j0 & 15);
  int h = j0 >> 4;
  int b = win >> 6, wi = (win >> 3) & 7, wj = win & 7;
  int qbase = wv*32;

  // Q fragments (pre-scaled by 32^-0.5*log2e in Q GEMM epilogue)
  s16x8 qb[2];
  #pragma unroll
  for(int nt = 0; nt < 2; nt++){
    int q = qbase + nt*16 + l15;
    long tok = (long)b*16384 + (wi*16 + (q>>4))*128 + wj*16 + (q&15);
    qb[nt] = *(const s16x8*)(qmat + tok*192 + h*32 + lg*8);
  }
  // bias base pointers (one per nt)
  const unsigned short* bq[2];
  #pragma unroll
  for(int nt = 0; nt < 2; nt++)
    bq[nt] = bt + h*147456 + lg*2048 + (qbase + nt*16 + l15)*8;

  float m_run[2] = {-1e30f, -1e30f};
  float l_run[2] = {0.f, 0.f};
  f32x4 oacc[2][2];
  #pragma unroll
  for(int mtd=0;mtd<2;mtd++)
    #pragma unroll
    for(int nt=0;nt<2;nt++) oacc[mtd][nt] = (f32x4){0.f,0.f,0.f,0.f};

  for(int ch = 0; ch < 3; ch++){
    __syncthreads();
    // stage K (row-permuted) + V (transposed); 1536 vec-units / 512 threads = 3 each
    #pragma unroll
    for(int i = 0; i < 3; i++){
      int u = i*512 + tid;
      int p = u >> 3, w8 = u & 7;
      int isV = w8 >> 2, c = w8 & 3;
      int gp = ch*192 + p; int ii = gp / 24, jc = gp - ii*24;
      int gr = wi*16 - 4 + ii, gc = wj*16 - 4 + jc;
      bool ok = (gr >= 0) && (gr < 128) && (gc >= 0) && (gc < 128);
      s16x8 v = (s16x8){0,0,0,0,0,0,0,0};
      if(ok){
        long tok = (long)b*16384 + gr*128 + gc;
        v = *(const s16x8*)(kvmat + tok*384 + isV*192 + h*32 + c*8);
      }
      if(isV == 0){
        int pl = p & 31;
        int srow = (p & ~31) + ((pl & 4) << 2) + ((pl >> 3) << 2) + (pl & 3);
        *(s16x8*)(Kl + srow*40 + c*8) = v;
      } else {
        #pragma unroll
        for(int j2 = 0; j2 < 8; j2++) Vl[(c*8 + j2)*202 + p] = (unsigned short)v[j2];
      }
    }
    __syncthreads();
    #pragma unroll 1
    for(int kt = 0; kt < 6; kt++){
      int kb = kt*32;
      int step = ch*6 + kt;
      s16x8 ka[2];
      #pragma unroll
      for(int mt = 0; mt < 2; mt++) ka[mt] = *(const s16x8*)(Kl + (kb + mt*16 + l15)*40 + lg*8);
      f32x4 zf = (f32x4){0.f,0.f,0.f,0.f};
      f32x4 s[2][2];
      #pragma unroll
      for(int mt = 0; mt < 2; mt++)
        #pragma unroll
        for(int nt = 0; nt < 2; nt++)
          s[mt][nt] = __builtin_amdgcn_mfma_f32_16x16x32_bf16(ka[mt], qb[nt], zf, 0, 0, 0);
      // bias: one 16B load per nt; value idx = mt*4+r  (kpos = kb + lg*8 + mt*4 + r)
      #pragma unroll
      for(int nt = 0; nt < 2; nt++){
        s16x8 bv = *(const s16x8*)(bq[nt] + step*8192);
        #pragma unroll
        for(int mt = 0; mt < 2; mt++)
          #pragma unroll
          for(int r = 0; r < 4; r++) s[mt][nt][r] += b2f((unsigned short)bv[mt*4 + r]);
      }
      // online softmax over 32 kv (log2 domain)
      float lm[2];
      #pragma unroll
      for(int nt = 0; nt < 2; nt++){
        float v0 = fmaxf(fmaxf(s[0][nt][0], s[0][nt][1]), s[0][nt][2]);
        float v1 = fmaxf(fmaxf(s[0][nt][3], s[1][nt][0]), s[1][nt][1]);
        float v2 = fmaxf(fmaxf(s[1][nt][2], s[1][nt][3]), v0);
        float v = fmaxf(v1, v2);
        v = fmaxf(v, __shfl_xor(v, 16));
        v = fmaxf(v, __shfl_xor(v, 32));
        lm[nt] = v;
      }
      if(__any((lm[0] > m_run[0]) || (lm[1] > m_run[1]))){
        #pragma unroll
        for(int nt = 0; nt < 2; nt++){
          float nm = fmaxf(m_run[nt], lm[nt]);
          float fac = ex2(m_run[nt] - nm);
          m_run[nt] = nm;
          l_run[nt] *= fac;
          #pragma unroll
          for(int mtd = 0; mtd < 2; mtd++)
            #pragma unroll
            for(int r = 0; r < 4; r++) oacc[mtd][nt][r] *= fac;
        }
      }
      // P = 2^(S-m) packed directly into PV B-fragment
      s16x8 pb[2];
      #pragma unroll
      for(int nt = 0; nt < 2; nt++){
        float p0 = ex2(s[0][nt][0] - m_run[nt]);
        float p1 = ex2(s[0][nt][1] - m_run[nt]);
        float p2 = ex2(s[0][nt][2] - m_run[nt]);
        float p3 = ex2(s[0][nt][3] - m_run[nt]);
        float p4 = ex2(s[1][nt][0] - m_run[nt]);
        float p5 = ex2(s[1][nt][1] - m_run[nt]);
        float p6 = ex2(s[1][nt][2] - m_run[nt]);
        float p7 = ex2(s[1][nt][3] - m_run[nt]);
        l_run[nt] += ((p0+p1)+(p2+p3)) + ((p4+p5)+(p6+p7));
        unsigned int w[4];
        w[0] = pk_bf16(p0, p1); w[1] = pk_bf16(p2, p3);
        w[2] = pk_bf16(p4, p5); w[3] = pk_bf16(p6, p7);
        pb[nt] = __builtin_bit_cast(s16x8, w);
      }
      s16x8 va[2];
      #pragma unroll
      for(int mtd = 0; mtd < 2; mtd++) va[mtd] = *(const s16x8*)(Vl + (mtd*16 + l15)*202 + kb + lg*8);
      #pragma unroll
      for(int mtd = 0; mtd < 2; mtd++)
        #pragma unroll
        for(int nt = 0; nt < 2; nt++)
          oacc[mtd][nt] = __builtin_amdgcn_mfma_f32_16x16x32_bf16(va[mtd], pb[nt], oacc[mtd][nt], 0, 0, 0);
    }
  }
  #pragma unroll
  for(int nt = 0; nt < 2; nt++){
    float l = l_run[nt];
    l += __shfl_xor(l, 16);
    l += __shfl_xor(l, 32);
    float inv = 1.f / l;
    int q = qbase + nt*16 + l15;
    long tok = (long)b*16384 + (wi*16 + (q>>4))*128 + wj*16 + (q&15);
    #pragma unroll
    for(int mtd = 0; mtd < 2; mtd++){
      s16x4 o;
      #pragma unroll
      for(int r = 0; r < 4; r++) o[r] = (short)f2b(oacc[mtd][nt][r] * inv);
      *(s16x4*)(omat + tok*192 + h*32 + mtd*16 + lg*4) = o;
    }
  }
}

// ---------------- proj + residual + LN2 fused: 64 rows x full 192 cols per block ----------------
__global__ __launch_bounds__(256) void proj_ln(
    const unsigned short* __restrict__ A, const unsigned short* __restrict__ W,
    const float* __restrict__ bias, const unsigned short* __restrict__ resb,
    const float* __restrict__ g2, const float* __restrict__ b2,
    float* __restrict__ r2, unsigned short* __restrict__ n2){
  extern __shared__ char smem[];
  unsigned short* Bl = (unsigned short*)smem;             // [192][200] = 76800B
  float* ps = (float*)(smem + 76800);                     // [4][64]
  float* pq = (float*)(smem + 77824);                     // [4][64]
  float* mu_s = (float*)(smem + 78848);                   // [64]
  float* rs_s = (float*)(smem + 79104);                   // [64] -> 79360B total
  int tid = threadIdx.x, lane = tid & 63, wv = tid >> 6;
  int l15 = lane & 15, lg = lane >> 4;
  long rowbase = (long)blockIdx.x * 64;
  for(int u = tid; u < 192*24; u += 256){
    int row = u / 24, c = u - row*24;
    *(s16x8*)(Bl + row*200 + c*8) = *(const s16x8*)(W + row*192 + c*8);
  }
  __syncthreads();
  const unsigned short* ap[4];
  #pragma unroll
  for(int m = 0; m < 4; m++) ap[m] = A + (rowbase + m*16 + l15)*192 + lg*8;
  f32x4 acc[4][3];
  #pragma unroll
  for(int m=0;m<4;m++)
    #pragma unroll
    for(int n=0;n<3;n++) acc[m][n] = (f32x4){0.f,0.f,0.f,0.f};
  #pragma unroll 3
  for(int kk = 0; kk < 6; kk++){
    s16x8 af[4], bf[3];
    #pragma unroll
    for(int m = 0; m < 4; m++) af[m] = *(const s16x8*)(ap[m] + kk*32);
    #pragma unroll
    for(int n = 0; n < 3; n++) bf[n] = *(const s16x8*)(Bl + (wv*48 + n*16 + l15)*200 + kk*32 + lg*8);
    #pragma unroll
    for(int m = 0; m < 4; m++)
      #pragma unroll
      for(int n = 0; n < 3; n++)
        acc[m][n] = __builtin_amdgcn_mfma_f32_16x16x32_bf16(af[m], bf[n], acc[m][n], 0, 0, 0);
  }
  float val[4][3][4];
  float ts[4][4], tq[4][4];
  #pragma unroll
  for(int m=0;m<4;m++)
    #pragma unroll
    for(int r=0;r<4;r++){ ts[m][r]=0.f; tq[m][r]=0.f; }
  #pragma unroll
  for(int n = 0; n < 3; n++){
    int colg = wv*48 + n*16 + l15;
    float bs = bias[colg];
    #pragma unroll
    for(int m = 0; m < 4; m++){
      long rowg = rowbase + m*16 + lg*4;
      #pragma unroll
      for(int r = 0; r < 4; r++){
        long idx = (rowg + r)*192 + colg;
        float v = acc[m][n][r] + bs + b2f(resb[idx]);
        val[m][n][r] = v;
        ts[m][r] += v; tq[m][r] += v*v;
        r2[idx] = v;
      }
    }
  }
  #pragma unroll
  for(int m = 0; m < 4; m++)
    #pragma unroll
    for(int r = 0; r < 4; r++){
      float s1 = ts[m][r], q1 = tq[m][r];
      #pragma unroll
      for(int off = 1; off < 16; off <<= 1){
        s1 += __shfl_xor(s1, off);
        q1 += __shfl_xor(q1, off);
      }
      if(l15 == 0){
        int row = m*16 + lg*4 + r;
        ps[wv*64 + row] = s1; pq[wv*64 + row] = q1;
      }
    }
  __syncthreads();
  if(tid < 64){
    float ss = ps[tid] + ps[64+tid] + ps[128+tid] + ps[192+tid];
    float qq = pq[tid] + pq[64+tid] + pq[128+tid] + pq[192+tid];
    float mu = ss * (1.f/192.f);
    float var = qq * (1.f/192.f) - mu*mu;
    mu_s[tid] = mu; rs_s[tid] = 1.f/sqrtf(var + 1e-5f);
  }
  __syncthreads();
  #pragma unroll
  for(int n = 0; n < 3; n++){
    int colg = wv*48 + n*16 + l15;
    float gg = g2[colg], bb = b2[colg];
    #pragma unroll
    for(int m = 0; m < 4; m++){
      long rowg = rowbase + m*16 + lg*4;
      #pragma unroll
      for(int r = 0; r < 4; r++){
        int row = m*16 + lg*4 + r;
        long idx = (rowg + r)*192 + colg;
        n2[idx] = f2b((val[m][n][r] - mu_s[row]) * rs_s[row] * gg + bb);
      }
    }
  }
}

extern "C" void kernel_launch(void* const* d_in, const int* in_sizes, int n_in,
                              void* d_out, int out_size, void* d_ws, size_t ws_size,
                              hipStream_t stream) {
  const float* x     = (const float*)d_in[0];
  const float* depth = (const float*)d_in[1];
  const int*   rpi   = (const int*)d_in[2];
  const float* n1w   = (const float*)d_in[3];
  const float* n1b   = (const float*)d_in[4];
  const float* qkvw  = (const float*)d_in[5];
  const float* qkvb  = (const float*)d_in[6];
  const float* dprjw = (const float*)d_in[7];
  const float* dprjb = (const float*)d_in[8];
  const float* rpb   = (const float*)d_in[9];
  const float* prjw  = (const float*)d_in[10];
  const float* prjb  = (const float*)d_in[11];
  const float* n2w   = (const float*)d_in[12];
  const float* n2b   = (const float*)d_in[13];
  const float* fc1w  = (const float*)d_in[14];
  const float* fc1b  = (const float*)d_in[15];
  const float* fc2w  = (const float*)d_in[16];
  const float* fc2b  = (const float*)d_in[17];

  char* ws = (char*)d_ws;
  unsigned short* xn  = (unsigned short*)(ws + 0);          // 12.6MB (dead after KV gemm)
  unsigned short* dn  = (unsigned short*)(ws + 12582912);   // 12.6MB (dead after Q gemm)
  unsigned short* xf  = (unsigned short*)(ws + 25165824);   // 12.6MB (dead after proj_ln)
  unsigned short* kv  = (unsigned short*)(ws + 37748736);   // 25.2MB (dead after attn)
  unsigned short* h1  = (unsigned short*)(ws + 37748736);   //   overlays kv
  unsigned short* qm  = (unsigned short*)(ws + 62914560);   // 12.6MB (dead after attn)
  float*          r2  = (float*)(ws + 75497472);            // 25.2MB
  unsigned short* om  = (unsigned short*)(ws + 100663296);  // 12.6MB (dead after proj_ln)
  unsigned short* n2  = (unsigned short*)(ws + 100663296);  //   overlays om (safe: barriers)
  unsigned short* kvw = (unsigned short*)(ws + 113246208);
  unsigned short* dpw = (unsigned short*)(ws + 113393664);
  unsigned short* pjw = (unsigned short*)(ws + 113467392);
  unsigned short* f1w = (unsigned short*)(ws + 113541120);
  unsigned short* f2w = (unsigned short*)(ws + 113688576);
  unsigned short* bt  = (unsigned short*)(ws + 113836032);  // 1769472B -> end 115605504

  prep_all<<<5120, 256, 0, stream>>>(x, depth, n1w, n1b, qkvw, dprjw, prjw, fc1w, fc2w,
                                     rpi, rpb, xn, xf, dn, kvw, dpw, pjw, f1w, f2w, bt);
  gemm_kvq<<<2304, 256, 25600, stream>>>(xn, dn, kvw, dpw, qkvb + 192, dprjb, kv, qm);
  attn_k<<<768, 512, 0, stream>>>(qm, kv, bt, om);
  proj_ln<<<512, 256, 79360, stream>>>(om, pjw, prjb, xf, n2w, n2b, r2, n2);
  gemm2<<<1536, 256, 25600, stream>>>(n2, f1w, fc1b, nullptr, h1, 192, 384, 1);
  gemm2<<<768, 256, 50176, stream>>>(h1, f2w, fc2b, r2, d_out, 384, 192, 8);
}

// Round 6
// 156.022 us; speedup vs baseline: 1.6507x; 1.3290x over previous
//
#include <hip/hip_runtime.h>
#include <math.h>

typedef __attribute__((ext_vector_type(8))) short s16x8;
typedef __attribute__((ext_vector_type(4))) short s16x4;
typedef __attribute__((ext_vector_type(4))) float f32x4;

#define DEV __device__ __forceinline__

DEV float b2f(unsigned short u){ unsigned int x = ((unsigned int)u)<<16u; return __builtin_bit_cast(float,x); }
DEV unsigned short f2b(float f){
  unsigned int x = __builtin_bit_cast(unsigned int,f);
  x += 0x7fffu + ((x>>16)&1u);
  return (unsigned short)(x>>16);
}
DEV unsigned int pk_bf16(float lo, float hi){
  unsigned int r;
  asm("v_cvt_pk_bf16_f32 %0, %1, %2" : "=v"(r) : "v"(lo), "v"(hi));
  return r;
}
DEV float ex2(float x){  // 2^x, native
  float r;
  asm("v_exp_f32 %0, %1" : "=v"(r) : "v"(x));
  return r;
}
DEV float rcpf(float x){
  float r;
  asm("v_rcp_f32 %0, %1" : "=v"(r) : "v"(x));
  return r;
}
#define LOG2E 1.4426950408889634f

// ---------------- prep_all: [0,512) = transpose+LN1, [512,5120) = weights + bias table ----
__global__ __launch_bounds__(256) void prep_all(
    const float* __restrict__ x, const float* __restrict__ depth,
    const float* __restrict__ g, const float* __restrict__ be,
    const float* __restrict__ qkvw, const float* __restrict__ dprojw,
    const float* __restrict__ projw, const float* __restrict__ fc1w,
    const float* __restrict__ fc2w, const int* __restrict__ rpi,
    const float* __restrict__ rpb,
    unsigned short* xn, unsigned short* xf, unsigned short* dn,
    unsigned short* kvw, unsigned short* dpw, unsigned short* pjw,
    unsigned short* f1w, unsigned short* f2w, unsigned short* bt){
  __shared__ float t[64][193];
  __shared__ float ps[4][64], pq[4][64];
  __shared__ float mu_s[64], rs_s[64];
  int tid = threadIdx.x;
  int bid = blockIdx.x;
  if(bid >= 512){
    int i = (bid - 512)*256 + tid;
    if(i < 73728){                       // kvw [384][192] = qkv_w[:,192+n]
      int n = i/192, k = i - n*192;
      kvw[i] = f2b(qkvw[k*576 + 192 + n]);
    } else if(i < 110592){               // dpw: dproj_w already [out][in]
      int j = i - 73728;
      dpw[j] = f2b(dprojw[j]);
    } else if(i < 147456){               // pjw [192][192]
      int j = i - 110592; int n = j/192, k = j - n*192;
      pjw[j] = f2b(projw[k*192 + n]);
    } else if(i < 221184){               // f1w [384][192]
      int j = i - 147456; int n = j/192, k = j - n*192;
      f1w[j] = f2b(fc1w[k*384 + n]);
    } else if(i < 294912){               // f2w [192][384]
      int j = i - 221184; int n = j/384, k = j - n*384;
      f2w[j] = f2b(fc2w[k*192 + n]);
    } else {                             // bias_t [h][step18][lg4][q256][8], pre-multiplied by log2e
      int j = i - 294912;
      int h = j/147456; int rr = j - h*147456;
      int kk = rr >> 8; int q = rr & 255;
      int step = kk >> 5, within = kk & 31;
      int lg = within >> 3, p4r = within & 7;
      bt[h*147456 + step*8192 + lg*2048 + q*8 + p4r] =
          f2b(rpb[rpi[q*576 + kk]*6 + h] * LOG2E);
    }
    return;
  }
  long tokbase = (long)bid * 64;
  int b = (int)(tokbase >> 14); int hw = (int)(tokbase & 16383);
  const float* xb = x + ((long)b*192)*16384 + hw;
  int tok = tid & 63, cpart = tid >> 6;
  for(int c = cpart; c < 192; c += 4) t[tok][c] = xb[(long)c*16384 + tok];
  __syncthreads();
  float s = 0.f, q = 0.f;
  #pragma unroll 4
  for(int i = 0; i < 48; i++){ float v = t[tok][cpart*48 + i]; s += v; q += v*v; }
  ps[cpart][tok] = s; pq[cpart][tok] = q;
  __syncthreads();
  if(tid < 64){
    float ss = ps[0][tid]+ps[1][tid]+ps[2][tid]+ps[3][tid];
    float qq = pq[0][tid]+pq[1][tid]+pq[2][tid]+pq[3][tid];
    float mu = ss * (1.f/192.f);
    float var = qq * (1.f/192.f) - mu*mu;
    mu_s[tid] = mu; rs_s[tid] = 1.f/sqrtf(var + 1e-5f);
  }
  __syncthreads();
  long obase = tokbase * 192;
  for(int u = tid; u < 64*192; u += 256){
    int tk = u / 192, ch = u - tk*192;
    float v = t[tk][ch];
    xf[obase + u] = f2b(v);
    xn[obase + u] = f2b((v - mu_s[tk]) * rs_s[tk] * g[ch] + be[ch]);
  }
  __syncthreads();
  const float* db = depth + ((long)b*192)*16384 + hw;
  for(int c = cpart; c < 192; c += 4) t[tok][c] = db[(long)c*16384 + tok];
  __syncthreads();
  for(int u = tid; u < 64*192; u += 256){
    int tk = u / 192, ch = u - tk*192;
    dn[obase + u] = f2b(t[tk][ch]);
  }
}

// ---------------- GEMM body: tile 128x64, LDS-staged A and B (round-2 structure) ----------
// flags: 1=gelu(tanh/sigmoid approx), 4=*(attn_scale*log2e), 8=fc2 (f32 NCHW out, +resf)
// smem: Al = smem[0..9216) shorts, Bl = smem[9216..13824) shorts. fc2 epilogue T needs 33792B.
DEV void gemm_body(const unsigned short* __restrict__ A, const unsigned short* __restrict__ W,
                   const float* __restrict__ bias, const float* __restrict__ resf,
                   void* outp, int K, int N, int flags, int bid,
                   unsigned short* smem, int tid){
  unsigned short* Al = smem;            // [128][72]
  unsigned short* Bl = smem + 9216;     // [64][72]
  int lane = tid & 63, wv = tid >> 6;
  int wm = wv >> 1, wn = wv & 1, l15 = lane & 15, lg = lane >> 4;
  int X = bid & 7, j = bid >> 3;
  int mb = X + 8*(j & 31);
  int nb = j >> 5;
  long rowbase = (long)mb * 128;
  int colbase = nb * 64;
  f32x4 acc[4][2];
  #pragma unroll
  for(int m=0;m<4;m++)
    #pragma unroll
    for(int n=0;n<2;n++) acc[m][n] = (f32x4){0.f,0.f,0.f,0.f};
  int nk = K >> 6;
  for(int kt = 0; kt < nk; kt++){
    int k0 = kt*64;
    #pragma unroll
    for(int i = 0; i < 4; i++){
      int u = i*256 + tid; int r = u >> 3, c = u & 7;
      *(s16x8*)(Al + r*72 + c*8) = *(const s16x8*)(A + (rowbase + r)*(long)K + k0 + c*8);
    }
    #pragma unroll
    for(int i = 0; i < 2; i++){
      int u = i*256 + tid; int r = u >> 3, c = u & 7;
      *(s16x8*)(Bl + r*72 + c*8) = *(const s16x8*)(W + (long)(colbase + r)*K + k0 + c*8);
    }
    __syncthreads();
    #pragma unroll
    for(int kk = 0; kk < 64; kk += 32){
      s16x8 af[4], bf[2];
      #pragma unroll
      for(int m = 0; m < 4; m++) af[m] = *(const s16x8*)(Al + (wm*64 + m*16 + l15)*72 + kk + lg*8);
      #pragma unroll
      for(int n = 0; n < 2; n++) bf[n] = *(const s16x8*)(Bl + (wn*32 + n*16 + l15)*72 + kk + lg*8);
      #pragma unroll
      for(int m = 0; m < 4; m++)
        #pragma unroll
        for(int n = 0; n < 2; n++)
          acc[m][n] = __builtin_amdgcn_mfma_f32_16x16x32_bf16(af[m], bf[n], acc[m][n], 0, 0, 0);
    }
    __syncthreads();
  }
  if(flags & 8){
    // fc2: v = acc + bias + resf; transpose via LDS; coalesced NCHW f32 store
    float vloc[2][4][4];
    #pragma unroll
    for(int n = 0; n < 2; n++){
      int colg = colbase + wn*32 + n*16 + l15;
      float bs = bias[colg];
      #pragma unroll
      for(int m = 0; m < 4; m++){
        long rowg = rowbase + wm*64 + m*16 + lg*4;
        #pragma unroll
        for(int r = 0; r < 4; r++){
          long idx = (rowg + r)*(long)N + colg;
          vloc[n][m][r] = acc[m][n][r] + bs + resf[idx];
        }
      }
    }
    float* T = (float*)smem;      // [64 ch][132 tok] = 33792B (dynamic alloc covers)
    #pragma unroll
    for(int n = 0; n < 2; n++){
      int chl = wn*32 + n*16 + l15;
      #pragma unroll
      for(int m = 0; m < 4; m++){
        int tl = wm*64 + m*16 + lg*4;
        #pragma unroll
        for(int r = 0; r < 4; r++) T[chl*132 + tl + r] = vloc[n][m][r];
      }
    }
    __syncthreads();
    int bb = (int)(rowbase >> 14), hw0 = (int)(rowbase & 16383);
    float* op = (float*)outp;
    for(int u = tid; u < 8192; u += 256){
      int chn = u >> 7, t2 = u & 127;
      op[((long)bb*192 + colbase + chn)*16384 + hw0 + t2] = T[chn*132 + t2];
    }
    return;
  }
  // bf16 epilogue: apply flags, bounce through LDS, vectorized coalesced stores
  unsigned short* Ct = smem;    // [128][72] reuse Al region
  #pragma unroll
  for(int n = 0; n < 2; n++){
    int colg_l = wn*32 + n*16 + l15;
    float bs = bias[colbase + colg_l];
    #pragma unroll
    for(int m = 0; m < 4; m++){
      int rowl = wm*64 + m*16 + lg*4;
      #pragma unroll
      for(int r = 0; r < 4; r++){
        float v = acc[m][n][r] + bs;
        if(flags & 1){
          // gelu(x) = x * sigmoid(1.5957691x + 0.0713548x^3)  [tanh approx, exp2 domain]
          float x2 = v*v;
          float u2 = -2.3021174f - 0.10294418f*x2;
          float sg = ex2(v*u2);            // e^{-2y}
          v = v * rcpf(1.f + sg);
        }
        if(flags & 4) v *= (0.17677669529663687f * LOG2E);   // 32^-0.5 * log2e
        Ct[(rowl + r)*72 + colg_l] = f2b(v);
      }
    }
  }
  __syncthreads();
  unsigned short* op = (unsigned short*)outp;
  #pragma unroll
  for(int i = 0; i < 4; i++){
    int u = i*256 + tid;
    int tok = u >> 3, c8 = u & 7;
    *(s16x8*)(op + (rowbase + tok)*(long)N + colbase + c8*8) = *(const s16x8*)(Ct + tok*72 + c8*8);
  }
}

// KV gemm (blocks 0..1535) + Q gemm (1536..2303) in one dispatch
__global__ __launch_bounds__(256) void gemm_kvq(
    const unsigned short* __restrict__ xn, const unsigned short* __restrict__ dn,
    const unsigned short* __restrict__ kvw, const unsigned short* __restrict__ dpw,
    const float* __restrict__ kvb, const float* __restrict__ dpb,
    unsigned short* kv, unsigned short* qm){
  extern __shared__ unsigned short Bl[];
  int bid = blockIdx.x, tid = threadIdx.x;
  if(bid < 1536) gemm_body(xn, kvw, kvb, nullptr, kv, 192, 384, 0, bid, Bl, tid);
  else           gemm_body(dn, dpw, dpb, nullptr, qm, 192, 192, 4, bid - 1536, Bl, tid);
}

__global__ __launch_bounds__(256) void gemm2(
    const unsigned short* __restrict__ A, const unsigned short* __restrict__ W,
    const float* __restrict__ bias, const float* __restrict__ resf,
    void* outp, int K, int N, int flags){
  extern __shared__ unsigned short Bl[];
  gemm_body(A, W, bias, resf, outp, K, N, flags, blockIdx.x, Bl, threadIdx.x);
}

// ---------------- Attention ----------------
// 768 blocks = (win 128) x (h 6), XCD-swizzled. 8 waves x 32 q rows = 256 q.
// K staged row-permuted so QK^T output fragment == PV B-fragment (P stays in regs).
// 32-wide kv steps; logits in log2 domain (Q pre-scaled, bias pre-scaled by log2e).
__global__ __launch_bounds__(512, 6) void attn_k(
    const unsigned short* __restrict__ qmat, const unsigned short* __restrict__ kvmat,
    const unsigned short* __restrict__ bt, unsigned short* __restrict__ omat){
  __shared__ unsigned short Kl[192*40];   // permuted rows, stride 40
  __shared__ unsigned short Vl[32*202];   // [d][pos] transposed, stride 202
  int tid = threadIdx.x, lane = tid & 63, wv = tid >> 6;
  int l15 = lane & 15, lg = lane >> 4;
  int bid = blockIdx.x;
  int X = bid & 7, j0 = bid >> 3;
  int win = X + 8*(j0 & 15);
  int h = j0 >> 4;
  int b = win >> 6, wi = (win >> 3) & 7, wj = win & 7;
  int qbase = wv*32;

  // Q fragments (pre-scaled by 32^-0.5*log2e in Q GEMM epilogue)
  s16x8 qb[2];
  #pragma unroll
  for(int nt = 0; nt < 2; nt++){
    int q = qbase + nt*16 + l15;
    long tok = (long)b*16384 + (wi*16 + (q>>4))*128 + wj*16 + (q&15);
    qb[nt] = *(const s16x8*)(qmat + tok*192 + h*32 + lg*8);
  }
  // bias base pointers (one per nt)
  const unsigned short* bq[2];
  #pragma unroll
  for(int nt = 0; nt < 2; nt++)
    bq[nt] = bt + h*147456 + lg*2048 + (qbase + nt*16 + l15)*8;

  float m_run[2] = {-1e30f, -1e30f};
  float l_run[2] = {0.f, 0.f};
  f32x4 oacc[2][2];
  #pragma unroll
  for(int mtd=0;mtd<2;mtd++)
    #pragma unroll
    for(int nt=0;nt<2;nt++) oacc[mtd][nt] = (f32x4){0.f,0.f,0.f,0.f};

  for(int ch = 0; ch < 3; ch++){
    __syncthreads();
    // stage K (row-permuted) + V (transposed); 1536 vec-units / 512 threads = 3 each
    #pragma unroll
    for(int i = 0; i < 3; i++){
      int u = i*512 + tid;
      int p = u >> 3, w8 = u & 7;
      int isV = w8 >> 2, c = w8 & 3;
      int gp = ch*192 + p; int ii = gp / 24, jc = gp - ii*24;
      int gr = wi*16 - 4 + ii, gc = wj*16 - 4 + jc;
      bool ok = (gr >= 0) && (gr < 128) && (gc >= 0) && (gc < 128);
      s16x8 v = (s16x8){0,0,0,0,0,0,0,0};
      if(ok){
        long tok = (long)b*16384 + gr*128 + gc;
        v = *(const s16x8*)(kvmat + tok*384 + isV*192 + h*32 + c*8);
      }
      if(isV == 0){
        int pl = p & 31;
        int srow = (p & ~31) + ((pl & 4) << 2) + ((pl >> 3) << 2) + (pl & 3);
        *(s16x8*)(Kl + srow*40 + c*8) = v;
      } else {
        #pragma unroll
        for(int j2 = 0; j2 < 8; j2++) Vl[(c*8 + j2)*202 + p] = (unsigned short)v[j2];
      }
    }
    __syncthreads();
    #pragma unroll 1
    for(int kt = 0; kt < 6; kt++){
      int kb = kt*32;
      int step = ch*6 + kt;
      s16x8 ka[2];
      #pragma unroll
      for(int mt = 0; mt < 2; mt++) ka[mt] = *(const s16x8*)(Kl + (kb + mt*16 + l15)*40 + lg*8);
      f32x4 zf = (f32x4){0.f,0.f,0.f,0.f};
      f32x4 s[2][2];
      #pragma unroll
      for(int mt = 0; mt < 2; mt++)
        #pragma unroll
        for(int nt = 0; nt < 2; nt++)
          s[mt][nt] = __builtin_amdgcn_mfma_f32_16x16x32_bf16(ka[mt], qb[nt], zf, 0, 0, 0);
      // bias: one 16B load per nt; value idx = mt*4+r  (kpos = kb + lg*8 + mt*4 + r)
      #pragma unroll
      for(int nt = 0; nt < 2; nt++){
        s16x8 bv = *(const s16x8*)(bq[nt] + step*8192);
        #pragma unroll
        for(int mt = 0; mt < 2; mt++)
          #pragma unroll
          for(int r = 0; r < 4; r++) s[mt][nt][r] += b2f((unsigned short)bv[mt*4 + r]);
      }
      // online softmax over 32 kv (log2 domain)
      float lm[2];
      #pragma unroll
      for(int nt = 0; nt < 2; nt++){
        float v0 = fmaxf(fmaxf(s[0][nt][0], s[0][nt][1]), s[0][nt][2]);
        float v1 = fmaxf(fmaxf(s[0][nt][3], s[1][nt][0]), s[1][nt][1]);
        float v2 = fmaxf(fmaxf(s[1][nt][2], s[1][nt][3]), v0);
        float v = fmaxf(v1, v2);
        v = fmaxf(v, __shfl_xor(v, 16));
        v = fmaxf(v, __shfl_xor(v, 32));
        lm[nt] = v;
      }
      if(__any((lm[0] > m_run[0]) || (lm[1] > m_run[1]))){
        #pragma unroll
        for(int nt = 0; nt < 2; nt++){
          float nm = fmaxf(m_run[nt], lm[nt]);
          float fac = ex2(m_run[nt] - nm);
          m_run[nt] = nm;
          l_run[nt] *= fac;
          #pragma unroll
          for(int mtd = 0; mtd < 2; mtd++)
            #pragma unroll
            for(int r = 0; r < 4; r++) oacc[mtd][nt][r] *= fac;
        }
      }
      // P = 2^(S-m) packed directly into PV B-fragment
      s16x8 pb[2];
      #pragma unroll
      for(int nt = 0; nt < 2; nt++){
        float p0 = ex2(s[0][nt][0] - m_run[nt]);
        float p1 = ex2(s[0][nt][1] - m_run[nt]);
        float p2 = ex2(s[0][nt][2] - m_run[nt]);
        float p3 = ex2(s[0][nt][3] - m_run[nt]);
        float p4 = ex2(s[1][nt][0] - m_run[nt]);
        float p5 = ex2(s[1][nt][1] - m_run[nt]);
        float p6 = ex2(s[1][nt][2] - m_run[nt]);
        float p7 = ex2(s[1][nt][3] - m_run[nt]);
        l_run[nt] += ((p0+p1)+(p2+p3)) + ((p4+p5)+(p6+p7));
        unsigned int w[4];
        w[0] = pk_bf16(p0, p1); w[1] = pk_bf16(p2, p3);
        w[2] = pk_bf16(p4, p5); w[3] = pk_bf16(p6, p7);
        pb[nt] = __builtin_bit_cast(s16x8, w);
      }
      s16x8 va[2];
      #pragma unroll
      for(int mtd = 0; mtd < 2; mtd++) va[mtd] = *(const s16x8*)(Vl + (mtd*16 + l15)*202 + kb + lg*8);
      #pragma unroll
      for(int mtd = 0; mtd < 2; mtd++)
        #pragma unroll
        for(int nt = 0; nt < 2; nt++)
          oacc[mtd][nt] = __builtin_amdgcn_mfma_f32_16x16x32_bf16(va[mtd], pb[nt], oacc[mtd][nt], 0, 0, 0);
    }
  }
  #pragma unroll
  for(int nt = 0; nt < 2; nt++){
    float l = l_run[nt];
    l += __shfl_xor(l, 16);
    l += __shfl_xor(l, 32);
    float inv = 1.f / l;
    int q = qbase + nt*16 + l15;
    long tok = (long)b*16384 + (wi*16 + (q>>4))*128 + wj*16 + (q&15);
    #pragma unroll
    for(int mtd = 0; mtd < 2; mtd++){
      s16x4 o;
      #pragma unroll
      for(int r = 0; r < 4; r++) o[r] = (short)f2b(oacc[mtd][nt][r] * inv);
      *(s16x4*)(omat + tok*192 + h*32 + mtd*16 + lg*4) = o;
    }
  }
}

// ---------------- proj + residual + LN2 fused: 64 rows x full 192 cols per block ----------------
__global__ __launch_bounds__(256) void proj_ln(
    const unsigned short* __restrict__ A, const unsigned short* __restrict__ W,
    const float* __restrict__ bias, const unsigned short* __restrict__ resb,
    const float* __restrict__ g2, const float* __restrict__ b2,
    float* __restrict__ r2, unsigned short* __restrict__ n2){
  extern __shared__ char smem[];
  unsigned short* Bl = (unsigned short*)smem;             // [192][200] = 76800B
  float* ps = (float*)(smem + 76800);                     // [4][64]
  float* pq = (float*)(smem + 77824);                     // [4][64]
  float* mu_s = (float*)(smem + 78848);                   // [64]
  float* rs_s = (float*)(smem + 79104);                   // [64] -> 79360B total
  int tid = threadIdx.x, lane = tid & 63, wv = tid >> 6;
  int l15 = lane & 15, lg = lane >> 4;
  long rowbase = (long)blockIdx.x * 64;
  for(int u = tid; u < 192*24; u += 256){
    int row = u / 24, c = u - row*24;
    *(s16x8*)(Bl + row*200 + c*8) = *(const s16x8*)(W + row*192 + c*8);
  }
  __syncthreads();
  const unsigned short* ap[4];
  #pragma unroll
  for(int m = 0; m < 4; m++) ap[m] = A + (rowbase + m*16 + l15)*192 + lg*8;
  f32x4 acc[4][3];
  #pragma unroll
  for(int m=0;m<4;m++)
    #pragma unroll
    for(int n=0;n<3;n++) acc[m][n] = (f32x4){0.f,0.f,0.f,0.f};
  #pragma unroll 3
  for(int kk = 0; kk < 6; kk++){
    s16x8 af[4], bf[3];
    #pragma unroll
    for(int m = 0; m < 4; m++) af[m] = *(const s16x8*)(ap[m] + kk*32);
    #pragma unroll
    for(int n = 0; n < 3; n++) bf[n] = *(const s16x8*)(Bl + (wv*48 + n*16 + l15)*200 + kk*32 + lg*8);
    #pragma unroll
    for(int m = 0; m < 4; m++)
      #pragma unroll
      for(int n = 0; n < 3; n++)
        acc[m][n] = __builtin_amdgcn_mfma_f32_16x16x32_bf16(af[m], bf[n], acc[m][n], 0, 0, 0);
  }
  float val[4][3][4];
  float ts[4][4], tq[4][4];
  #pragma unroll
  for(int m=0;m<4;m++)
    #pragma unroll
    for(int r=0;r<4;r++){ ts[m][r]=0.f; tq[m][r]=0.f; }
  #pragma unroll
  for(int n = 0; n < 3; n++){
    int colg = wv*48 + n*16 + l15;
    float bs = bias[colg];
    #pragma unroll
    for(int m = 0; m < 4; m++){
      long rowg = rowbase + m*16 + lg*4;
      #pragma unroll
      for(int r = 0; r < 4; r++){
        long idx = (rowg + r)*192 + colg;
        float v = acc[m][n][r] + bs + b2f(resb[idx]);
        val[m][n][r] = v;
        ts[m][r] += v; tq[m][r] += v*v;
        r2[idx] = v;
      }
    }
  }
  #pragma unroll
  for(int m = 0; m < 4; m++)
    #pragma unroll
    for(int r = 0; r < 4; r++){
      float s1 = ts[m][r], q1 = tq[m][r];
      #pragma unroll
      for(int off = 1; off < 16; off <<= 1){
        s1 += __shfl_xor(s1, off);
        q1 += __shfl_xor(q1, off);
      }
      if(l15 == 0){
        int row = m*16 + lg*4 + r;
        ps[wv*64 + row] = s1; pq[wv*64 + row] = q1;
      }
    }
  __syncthreads();
  if(tid < 64){
    float ss = ps[tid] + ps[64+tid] + ps[128+tid] + ps[192+tid];
    float qq = pq[tid] + pq[64+tid] + pq[128+tid] + pq[192+tid];
    float mu = ss * (1.f/192.f);
    float var = qq * (1.f/192.f) - mu*mu;
    mu_s[tid] = mu; rs_s[tid] = 1.f/sqrtf(var + 1e-5f);
  }
  __syncthreads();
  #pragma unroll
  for(int n = 0; n < 3; n++){
    int colg = wv*48 + n*16 + l15;
    float gg = g2[colg], bb = b2[colg];
    #pragma unroll
    for(int m = 0; m < 4; m++){
      long rowg = rowbase + m*16 + lg*4;
      #pragma unroll
      for(int r = 0; r < 4; r++){
        int row = m*16 + lg*4 + r;
        long idx = (rowg + r)*192 + colg;
        n2[idx] = f2b((val[m][n][r] - mu_s[row]) * rs_s[row] * gg + bb);
      }
    }
  }
}

extern "C" void kernel_launch(void* const* d_in, const int* in_sizes, int n_in,
                              void* d_out, int out_size, void* d_ws, size_t ws_size,
                              hipStream_t stream) {
  const float* x     = (const float*)d_in[0];
  const float* depth = (const float*)d_in[1];
  const int*   rpi   = (const int*)d_in[2];
  const float* n1w   = (const float*)d_in[3];
  const float* n1b   = (const float*)d_in[4];
  const float* qkvw  = (const float*)d_in[5];
  const float* qkvb  = (const float*)d_in[6];
  const float* dprjw = (const float*)d_in[7];
  const float* dprjb = (const float*)d_in[8];
  const float* rpb   = (const float*)d_in[9];
  const float* prjw  = (const float*)d_in[10];
  const float* prjb  = (const float*)d_in[11];
  const float* n2w   = (const float*)d_in[12];
  const float* n2b   = (const float*)d_in[13];
  const float* fc1w  = (const float*)d_in[14];
  const float* fc1b  = (const float*)d_in[15];
  const float* fc2w  = (const float*)d_in[16];
  const float* fc2b  = (const float*)d_in[17];

  char* ws = (char*)d_ws;
  unsigned short* xn  = (unsigned short*)(ws + 0);          // 12.6MB (dead after KV gemm)
  unsigned short* dn  = (unsigned short*)(ws + 12582912);   // 12.6MB (dead after Q gemm)
  unsigned short* xf  = (unsigned short*)(ws + 25165824);   // 12.6MB (dead after proj_ln)
  unsigned short* kv  = (unsigned short*)(ws + 37748736);   // 25.2MB (dead after attn)
  unsigned short* h1  = (unsigned short*)(ws + 37748736);   //   overlays kv
  unsigned short* qm  = (unsigned short*)(ws + 62914560);   // 12.6MB (dead after attn)
  float*          r2  = (float*)(ws + 75497472);            // 25.2MB
  unsigned short* om  = (unsigned short*)(ws + 100663296);  // 12.6MB (dead after proj_ln)
  unsigned short* n2  = (unsigned short*)(ws + 100663296);  //   overlays om (safe: barriers)
  unsigned short* kvw = (unsigned short*)(ws + 113246208);
  unsigned short* dpw = (unsigned short*)(ws + 113393664);
  unsigned short* pjw = (unsigned short*)(ws + 113467392);
  unsigned short* f1w = (unsigned short*)(ws + 113541120);
  unsigned short* f2w = (unsigned short*)(ws + 113688576);
  unsigned short* bt  = (unsigned short*)(ws + 113836032);  // 1769472B -> end 115605504

  prep_all<<<5120, 256, 0, stream>>>(x, depth, n1w, n1b, qkvw, dprjw, prjw, fc1w, fc2w,
                                     rpi, rpb, xn, xf, dn, kvw, dpw, pjw, f1w, f2w, bt);
  gemm_kvq<<<2304, 256, 27648, stream>>>(xn, dn, kvw, dpw, qkvb + 192, dprjb, kv, qm);
  attn_k<<<768, 512, 0, stream>>>(qm, kv, bt, om);
  proj_ln<<<512, 256, 79360, stream>>>(om, pjw, prjb, xf, n2w, n2b, r2, n2);
  gemm2<<<1536, 256, 27648, stream>>>(n2, f1w, fc1b, nullptr, h1, 192, 384, 1);
  gemm2<<<768, 256, 33792, stream>>>(h1, f2w, fc2b, r2, d_out, 384, 192, 8);
}

// Round 9
// 144.051 us; speedup vs baseline: 1.7879x; 1.0831x over previous
//
#include <hip/hip_runtime.h>
#include <math.h>

typedef __attribute__((ext_vector_type(8))) short s16x8;
typedef __attribute__((ext_vector_type(4))) short s16x4;
typedef __attribute__((ext_vector_type(4))) float f32x4;

#define DEV __device__ __forceinline__

DEV float b2f(unsigned short u){ unsigned int x = ((unsigned int)u)<<16u; return __builtin_bit_cast(float,x); }
DEV unsigned short f2b(float f){
  unsigned int x = __builtin_bit_cast(unsigned int,f);
  x += 0x7fffu + ((x>>16)&1u);
  return (unsigned short)(x>>16);
}
DEV unsigned int pk_bf16(float lo, float hi){
  unsigned int r;
  asm("v_cvt_pk_bf16_f32 %0, %1, %2" : "=v"(r) : "v"(lo), "v"(hi));
  return r;
}
DEV float ex2(float x){  // 2^x, native
  float r;
  asm("v_exp_f32 %0, %1" : "=v"(r) : "v"(x));
  return r;
}
DEV float rcpf(float x){
  float r;
  asm("v_rcp_f32 %0, %1" : "=v"(r) : "v"(x));
  return r;
}
#define LOG2E 1.4426950408889634f

// ---------------- prep_all: [0,512) = transpose+LN1, [512,5120) = weights + bias table ----
__global__ __launch_bounds__(256) void prep_all(
    const float* __restrict__ x, const float* __restrict__ depth,
    const float* __restrict__ g, const float* __restrict__ be,
    const float* __restrict__ qkvw, const float* __restrict__ dprojw,
    const float* __restrict__ projw, const float* __restrict__ fc1w,
    const float* __restrict__ fc2w, const int* __restrict__ rpi,
    const float* __restrict__ rpb,
    unsigned short* xn, unsigned short* xf, unsigned short* dn,
    unsigned short* kvw, unsigned short* dpw, unsigned short* pjw,
    unsigned short* f1w, unsigned short* f2w, unsigned short* bt){
  __shared__ float t[64][193];
  __shared__ float ps[4][64], pq[4][64];
  __shared__ float mu_s[64], rs_s[64];
  int tid = threadIdx.x;
  int bid = blockIdx.x;
  if(bid >= 512){
    int i = (bid - 512)*256 + tid;
    if(i < 73728){                       // kvw [384][192] = qkv_w[:,192+n]
      int n = i/192, k = i - n*192;
      kvw[i] = f2b(qkvw[k*576 + 192 + n]);
    } else if(i < 110592){               // dpw: dproj_w already [out][in]
      int j = i - 73728;
      dpw[j] = f2b(dprojw[j]);
    } else if(i < 147456){               // pjw [192][192]
      int j = i - 110592; int n = j/192, k = j - n*192;
      pjw[j] = f2b(projw[k*192 + n]);
    } else if(i < 221184){               // f1w [384][192]
      int j = i - 147456; int n = j/192, k = j - n*192;
      f1w[j] = f2b(fc1w[k*384 + n]);
    } else if(i < 294912){               // f2w [192][384]
      int j = i - 221184; int n = j/384, k = j - n*384;
      f2w[j] = f2b(fc2w[k*192 + n]);
    } else {                             // bias_t [h][step18][lg4][q256][8], pre-multiplied by log2e
      int j = i - 294912;
      int h = j/147456; int rr = j - h*147456;
      int kk = rr >> 8; int q = rr & 255;
      int step = kk >> 5, within = kk & 31;
      int lg = within >> 3, p4r = within & 7;
      bt[h*147456 + step*8192 + lg*2048 + q*8 + p4r] =
          f2b(rpb[rpi[q*576 + kk]*6 + h] * LOG2E);
    }
    return;
  }
  long tokbase = (long)bid * 64;
  int b = (int)(tokbase >> 14); int hw = (int)(tokbase & 16383);
  const float* xb = x + ((long)b*192)*16384 + hw;
  int tok = tid & 63, cpart = tid >> 6;
  for(int c = cpart; c < 192; c += 4) t[tok][c] = xb[(long)c*16384 + tok];
  __syncthreads();
  float s = 0.f, q = 0.f;
  #pragma unroll 4
  for(int i = 0; i < 48; i++){ float v = t[tok][cpart*48 + i]; s += v; q += v*v; }
  ps[cpart][tok] = s; pq[cpart][tok] = q;
  __syncthreads();
  if(tid < 64){
    float ss = ps[0][tid]+ps[1][tid]+ps[2][tid]+ps[3][tid];
    float qq = pq[0][tid]+pq[1][tid]+pq[2][tid]+pq[3][tid];
    float mu = ss * (1.f/192.f);
    float var = qq * (1.f/192.f) - mu*mu;
    mu_s[tid] = mu; rs_s[tid] = 1.f/sqrtf(var + 1e-5f);
  }
  __syncthreads();
  long obase = tokbase * 192;
  for(int u = tid; u < 64*192; u += 256){
    int tk = u / 192, ch = u - tk*192;
    float v = t[tk][ch];
    xf[obase + u] = f2b(v);
    xn[obase + u] = f2b((v - mu_s[tk]) * rs_s[tk] * g[ch] + be[ch]);
  }
  __syncthreads();
  const float* db = depth + ((long)b*192)*16384 + hw;
  for(int c = cpart; c < 192; c += 4) t[tok][c] = db[(long)c*16384 + tok];
  __syncthreads();
  for(int u = tid; u < 64*192; u += 256){
    int tk = u / 192, ch = u - tk*192;
    dn[obase + u] = f2b(t[tk][ch]);
  }
}

// ---------------- GEMM body: tile 128x64, LDS-staged A and B ----------
// flags: 1=gelu, 2=f32 token-major out (+resb bf16), 4=*(attn_scale*log2e), 8=fc2 (f32 NCHW out, +resf)
DEV void gemm_body(const unsigned short* __restrict__ A, const unsigned short* __restrict__ W,
                   const float* __restrict__ bias, const unsigned short* __restrict__ resb,
                   const float* __restrict__ resf, void* outp, int K, int N, int flags, int bid,
                   unsigned short* smem, int tid){
  unsigned short* Al = smem;            // [128][72]
  unsigned short* Bl = smem + 9216;     // [64][72]
  int lane = tid & 63, wv = tid >> 6;
  int wm = wv >> 1, wn = wv & 1, l15 = lane & 15, lg = lane >> 4;
  int X = bid & 7, j = bid >> 3;
  int mb = X + 8*(j & 31);
  int nb = j >> 5;
  long rowbase = (long)mb * 128;
  int colbase = nb * 64;
  f32x4 acc[4][2];
  #pragma unroll
  for(int m=0;m<4;m++)
    #pragma unroll
    for(int n=0;n<2;n++) acc[m][n] = (f32x4){0.f,0.f,0.f,0.f};
  int nk = K >> 6;
  for(int kt = 0; kt < nk; kt++){
    int k0 = kt*64;
    #pragma unroll
    for(int i = 0; i < 4; i++){
      int u = i*256 + tid; int r = u >> 3, c = u & 7;
      *(s16x8*)(Al + r*72 + c*8) = *(const s16x8*)(A + (rowbase + r)*(long)K + k0 + c*8);
    }
    #pragma unroll
    for(int i = 0; i < 2; i++){
      int u = i*256 + tid; int r = u >> 3, c = u & 7;
      *(s16x8*)(Bl + r*72 + c*8) = *(const s16x8*)(W + (long)(colbase + r)*K + k0 + c*8);
    }
    __syncthreads();
    #pragma unroll
    for(int kk = 0; kk < 64; kk += 32){
      s16x8 af[4], bf[2];
      #pragma unroll
      for(int m = 0; m < 4; m++) af[m] = *(const s16x8*)(Al + (wm*64 + m*16 + l15)*72 + kk + lg*8);
      #pragma unroll
      for(int n = 0; n < 2; n++) bf[n] = *(const s16x8*)(Bl + (wn*32 + n*16 + l15)*72 + kk + lg*8);
      #pragma unroll
      for(int m = 0; m < 4; m++)
        #pragma unroll
        for(int n = 0; n < 2; n++)
          acc[m][n] = __builtin_amdgcn_mfma_f32_16x16x32_bf16(af[m], bf[n], acc[m][n], 0, 0, 0);
    }
    __syncthreads();
  }
  if(flags & 8){
    // fc2: v = acc + bias + resf; transpose via LDS; coalesced NCHW f32 store
    float vloc[2][4][4];
    #pragma unroll
    for(int n = 0; n < 2; n++){
      int colg = colbase + wn*32 + n*16 + l15;
      float bs = bias[colg];
      #pragma unroll
      for(int m = 0; m < 4; m++){
        long rowg = rowbase + wm*64 + m*16 + lg*4;
        #pragma unroll
        for(int r = 0; r < 4; r++){
          long idx = (rowg + r)*(long)N + colg;
          vloc[n][m][r] = acc[m][n][r] + bs + resf[idx];
        }
      }
    }
    float* T = (float*)smem;      // [64 ch][132 tok] = 33792B
    #pragma unroll
    for(int n = 0; n < 2; n++){
      int chl = wn*32 + n*16 + l15;
      #pragma unroll
      for(int m = 0; m < 4; m++){
        int tl = wm*64 + m*16 + lg*4;
        #pragma unroll
        for(int r = 0; r < 4; r++) T[chl*132 + tl + r] = vloc[n][m][r];
      }
    }
    __syncthreads();
    int bb = (int)(rowbase >> 14), hw0 = (int)(rowbase & 16383);
    float* op = (float*)outp;
    for(int u = tid; u < 8192; u += 256){
      int chn = u >> 7, t2 = u & 127;
      op[((long)bb*192 + colbase + chn)*16384 + hw0 + t2] = T[chn*132 + t2];
    }
    return;
  }
  if(flags & 2){
    // proj: v = acc + bias + b2f(resb); f32 token-major out via LDS bounce (coalesced 16B stores)
    float vloc[2][4][4];
    #pragma unroll
    for(int n = 0; n < 2; n++){
      int colg = colbase + wn*32 + n*16 + l15;
      float bs = bias[colg];
      #pragma unroll
      for(int m = 0; m < 4; m++){
        long rowg = rowbase + wm*64 + m*16 + lg*4;
        #pragma unroll
        for(int r = 0; r < 4; r++){
          long idx = (rowg + r)*(long)N + colg;
          vloc[n][m][r] = acc[m][n][r] + bs + b2f(resb[idx]);
        }
      }
    }
    float* T = (float*)smem;      // [128 rows][68] f32 = 34816B
    #pragma unroll
    for(int n = 0; n < 2; n++){
      int colg_l = wn*32 + n*16 + l15;
      #pragma unroll
      for(int m = 0; m < 4; m++){
        int rowl = wm*64 + m*16 + lg*4;
        #pragma unroll
        for(int r = 0; r < 4; r++) T[(rowl + r)*68 + colg_l] = vloc[n][m][r];
      }
    }
    __syncthreads();
    float* op = (float*)outp;
    #pragma unroll
    for(int i = 0; i < 8; i++){
      int u = i*256 + tid;
      int row = u >> 4, c4 = u & 15;
      *(f32x4*)(op + (rowbase + row)*(long)N + colbase + c4*4) = *(const f32x4*)(T + row*68 + c4*4);
    }
    return;
  }
  // bf16 epilogue: apply flags, bounce through LDS, vectorized coalesced stores
  unsigned short* Ct = smem;    // [128][72] reuse Al region
  #pragma unroll
  for(int n = 0; n < 2; n++){
    int colg_l = wn*32 + n*16 + l15;
    float bs = bias[colbase + colg_l];
    #pragma unroll
    for(int m = 0; m < 4; m++){
      int rowl = wm*64 + m*16 + lg*4;
      #pragma unroll
      for(int r = 0; r < 4; r++){
        float v = acc[m][n][r] + bs;
        if(flags & 1){
          // gelu(x) ~ x * sigmoid(1.5957691x + 0.0713548x^3)  [exp2 domain]
          float x2 = v*v;
          float u2 = -2.3021174f - 0.10294418f*x2;
          float sg = ex2(v*u2);
          v = v * rcpf(1.f + sg);
        }
        if(flags & 4) v *= (0.17677669529663687f * LOG2E);   // 32^-0.5 * log2e
        Ct[(rowl + r)*72 + colg_l] = f2b(v);
      }
    }
  }
  __syncthreads();
  unsigned short* op = (unsigned short*)outp;
  #pragma unroll
  for(int i = 0; i < 4; i++){
    int u = i*256 + tid;
    int tok = u >> 3, c8 = u & 7;
    *(s16x8*)(op + (rowbase + tok)*(long)N + colbase + c8*8) = *(const s16x8*)(Ct + tok*72 + c8*8);
  }
}

// KV gemm (blocks 0..1535) + Q gemm (1536..2303) in one dispatch
__global__ __launch_bounds__(256) void gemm_kvq(
    const unsigned short* __restrict__ xn, const unsigned short* __restrict__ dn,
    const unsigned short* __restrict__ kvw, const unsigned short* __restrict__ dpw,
    const float* __restrict__ kvb, const float* __restrict__ dpb,
    unsigned short* kv, unsigned short* qm){
  extern __shared__ unsigned short Bl[];
  int bid = blockIdx.x, tid = threadIdx.x;
  if(bid < 1536) gemm_body(xn, kvw, kvb, nullptr, nullptr, kv, 192, 384, 0, bid, Bl, tid);
  else           gemm_body(dn, dpw, dpb, nullptr, nullptr, qm, 192, 192, 4, bid - 1536, Bl, tid);
}

__global__ __launch_bounds__(256) void gemm2(
    const unsigned short* __restrict__ A, const unsigned short* __restrict__ W,
    const float* __restrict__ bias, const unsigned short* __restrict__ resb,
    const float* __restrict__ resf, void* outp, int K, int N, int flags){
  extern __shared__ unsigned short Bl[];
  gemm_body(A, W, bias, resb, resf, outp, K, N, flags, blockIdx.x, Bl, threadIdx.x);
}

// ---------------- Attention (round-6 proven version) ----------------
// 768 blocks = (win 128) x (h 6), XCD-swizzled. 8 waves x 32 q rows = 256 q.
// K staged row-permuted so QK^T output fragment == PV B-fragment (P stays in regs).
// 32-wide kv steps; logits in log2 domain (Q pre-scaled, bias pre-scaled by log2e).
__global__ __launch_bounds__(512, 6) void attn_k(
    const unsigned short* __restrict__ qmat, const unsigned short* __restrict__ kvmat,
    const unsigned short* __restrict__ bt, unsigned short* __restrict__ omat){
  __shared__ unsigned short Kl[192*40];   // permuted rows, stride 40
  __shared__ unsigned short Vl[32*202];   // [d][pos] transposed, stride 202
  int tid = threadIdx.x, lane = tid & 63, wv = tid >> 6;
  int l15 = lane & 15, lg = lane >> 4;
  int bid = blockIdx.x;
  int X = bid & 7, j0 = bid >> 3;
  int win = X + 8*(j0 & 15);
  int h = j0 >> 4;
  int b = win >> 6, wi = (win >> 3) & 7, wj = win & 7;
  int qbase = wv*32;

  // Q fragments (pre-scaled by 32^-0.5*log2e in Q GEMM epilogue)
  s16x8 qb[2];
  #pragma unroll
  for(int nt = 0; nt < 2; nt++){
    int q = qbase + nt*16 + l15;
    long tok = (long)b*16384 + (wi*16 + (q>>4))*128 + wj*16 + (q&15);
    qb[nt] = *(const s16x8*)(qmat + tok*192 + h*32 + lg*8);
  }
  // bias base pointers (one per nt)
  const unsigned short* bq[2];
  #pragma unroll
  for(int nt = 0; nt < 2; nt++)
    bq[nt] = bt + h*147456 + lg*2048 + (qbase + nt*16 + l15)*8;

  float m_run[2] = {-1e30f, -1e30f};
  float l_run[2] = {0.f, 0.f};
  f32x4 oacc[2][2];
  #pragma unroll
  for(int mtd=0;mtd<2;mtd++)
    #pragma unroll
    for(int nt=0;nt<2;nt++) oacc[mtd][nt] = (f32x4){0.f,0.f,0.f,0.f};

  for(int ch = 0; ch < 3; ch++){
    __syncthreads();
    // stage K (row-permuted) + V (transposed); 1536 vec-units / 512 threads = 3 each
    #pragma unroll
    for(int i = 0; i < 3; i++){
      int u = i*512 + tid;
      int p = u >> 3, w8 = u & 7;
      int isV = w8 >> 2, c = w8 & 3;
      int gp = ch*192 + p; int ii = gp / 24, jc = gp - ii*24;
      int gr = wi*16 - 4 + ii, gc = wj*16 - 4 + jc;
      bool ok = (gr >= 0) && (gr < 128) && (gc >= 0) && (gc < 128);
      s16x8 v = (s16x8){0,0,0,0,0,0,0,0};
      if(ok){
        long tok = (long)b*16384 + gr*128 + gc;
        v = *(const s16x8*)(kvmat + tok*384 + isV*192 + h*32 + c*8);
      }
      if(isV == 0){
        int pl = p & 31;
        int srow = (p & ~31) + ((pl & 4) << 2) + ((pl >> 3) << 2) + (pl & 3);
        *(s16x8*)(Kl + srow*40 + c*8) = v;
      } else {
        #pragma unroll
        for(int j2 = 0; j2 < 8; j2++) Vl[(c*8 + j2)*202 + p] = (unsigned short)v[j2];
      }
    }
    __syncthreads();
    #pragma unroll 1
    for(int kt = 0; kt < 6; kt++){
      int kb = kt*32;
      int step = ch*6 + kt;
      s16x8 ka[2];
      #pragma unroll
      for(int mt = 0; mt < 2; mt++) ka[mt] = *(const s16x8*)(Kl + (kb + mt*16 + l15)*40 + lg*8);
      f32x4 zf = (f32x4){0.f,0.f,0.f,0.f};
      f32x4 s[2][2];
      #pragma unroll
      for(int mt = 0; mt < 2; mt++)
        #pragma unroll
        for(int nt = 0; nt < 2; nt++)
          s[mt][nt] = __builtin_amdgcn_mfma_f32_16x16x32_bf16(ka[mt], qb[nt], zf, 0, 0, 0);
      // bias: one 16B load per nt; value idx = mt*4+r  (kpos = kb + lg*8 + mt*4 + r)
      #pragma unroll
      for(int nt = 0; nt < 2; nt++){
        s16x8 bv = *(const s16x8*)(bq[nt] + step*8192);
        #pragma unroll
        for(int mt = 0; mt < 2; mt++)
          #pragma unroll
          for(int r = 0; r < 4; r++) s[mt][nt][r] += b2f((unsigned short)bv[mt*4 + r]);
      }
      // online softmax over 32 kv (log2 domain)
      float lm[2];
      #pragma unroll
      for(int nt = 0; nt < 2; nt++){
        float v0 = fmaxf(fmaxf(s[0][nt][0], s[0][nt][1]), s[0][nt][2]);
        float v1 = fmaxf(fmaxf(s[0][nt][3], s[1][nt][0]), s[1][nt][1]);
        float v2 = fmaxf(fmaxf(s[1][nt][2], s[1][nt][3]), v0);
        float v = fmaxf(v1, v2);
        v = fmaxf(v, __shfl_xor(v, 16));
        v = fmaxf(v, __shfl_xor(v, 32));
        lm[nt] = v;
      }
      if(__any((lm[0] > m_run[0]) || (lm[1] > m_run[1]))){
        #pragma unroll
        for(int nt = 0; nt < 2; nt++){
          float nm = fmaxf(m_run[nt], lm[nt]);
          float fac = ex2(m_run[nt] - nm);
          m_run[nt] = nm;
          l_run[nt] *= fac;
          #pragma unroll
          for(int mtd = 0; mtd < 2; mtd++)
            #pragma unroll
            for(int r = 0; r < 4; r++) oacc[mtd][nt][r] *= fac;
        }
      }
      // P = 2^(S-m) packed directly into PV B-fragment
      s16x8 pb[2];
      #pragma unroll
      for(int nt = 0; nt < 2; nt++){
        float p0 = ex2(s[0][nt][0] - m_run[nt]);
        float p1 = ex2(s[0][nt][1] - m_run[nt]);
        float p2 = ex2(s[0][nt][2] - m_run[nt]);
        float p3 = ex2(s[0][nt][3] - m_run[nt]);
        float p4 = ex2(s[1][nt][0] - m_run[nt]);
        float p5 = ex2(s[1][nt][1] - m_run[nt]);
        float p6 = ex2(s[1][nt][2] - m_run[nt]);
        float p7 = ex2(s[1][nt][3] - m_run[nt]);
        l_run[nt] += ((p0+p1)+(p2+p3)) + ((p4+p5)+(p6+p7));
        unsigned int w[4];
        w[0] = pk_bf16(p0, p1); w[1] = pk_bf16(p2, p3);
        w[2] = pk_bf16(p4, p5); w[3] = pk_bf16(p6, p7);
        pb[nt] = __builtin_bit_cast(s16x8, w);
      }
      s16x8 va[2];
      #pragma unroll
      for(int mtd = 0; mtd < 2; mtd++) va[mtd] = *(const s16x8*)(Vl + (mtd*16 + l15)*202 + kb + lg*8);
      #pragma unroll
      for(int mtd = 0; mtd < 2; mtd++)
        #pragma unroll
        for(int nt = 0; nt < 2; nt++)
          oacc[mtd][nt] = __builtin_amdgcn_mfma_f32_16x16x32_bf16(va[mtd], pb[nt], oacc[mtd][nt], 0, 0, 0);
    }
  }
  #pragma unroll
  for(int nt = 0; nt < 2; nt++){
    float l = l_run[nt];
    l += __shfl_xor(l, 16);
    l += __shfl_xor(l, 32);
    float inv = 1.f / l;
    int q = qbase + nt*16 + l15;
    long tok = (long)b*16384 + (wi*16 + (q>>4))*128 + wj*16 + (q&15);
    #pragma unroll
    for(int mtd = 0; mtd < 2; mtd++){
      s16x4 o;
      #pragma unroll
      for(int r = 0; r < 4; r++) o[r] = (short)f2b(oacc[mtd][nt][r] * inv);
      *(s16x4*)(omat + tok*192 + h*32 + mtd*16 + lg*4) = o;
    }
  }
}

// ---------------- LN2: streaming, 4 lanes per token ----------------
__global__ __launch_bounds__(256) void ln2_k(
    const float* __restrict__ in, const float* __restrict__ g,
    const float* __restrict__ be, unsigned short* __restrict__ out){
  int tid = threadIdx.x;
  long tok = (long)blockIdx.x*64 + (tid >> 2);
  int cpart = tid & 3;                    // 48 channels each
  const float* ip = in + tok*192 + cpart*48;
  f32x4 v[12];
  float s = 0.f, q = 0.f;
  #pragma unroll
  for(int i = 0; i < 12; i++){
    v[i] = *(const f32x4*)(ip + i*4);
    #pragma unroll
    for(int r = 0; r < 4; r++){ s += v[i][r]; q += v[i][r]*v[i][r]; }
  }
  s += __shfl_xor(s, 1); s += __shfl_xor(s, 2);
  q += __shfl_xor(q, 1); q += __shfl_xor(q, 2);
  float mu = s * (1.f/192.f);
  float var = q * (1.f/192.f) - mu*mu;
  float rs = 1.f/sqrtf(var + 1e-5f);
  unsigned short* op = out + tok*192 + cpart*48;
  const float* gp = g + cpart*48;
  const float* bp = be + cpart*48;
  #pragma unroll
  for(int i = 0; i < 12; i++){
    f32x4 g4 = *(const f32x4*)(gp + i*4);
    f32x4 b4 = *(const f32x4*)(bp + i*4);
    float o0 = (v[i][0] - mu)*rs*g4[0] + b4[0];
    float o1 = (v[i][1] - mu)*rs*g4[1] + b4[1];
    float o2 = (v[i][2] - mu)*rs*g4[2] + b4[2];
    float o3 = (v[i][3] - mu)*rs*g4[3] + b4[3];
    uint2 pk;
    pk.x = pk_bf16(o0, o1);
    pk.y = pk_bf16(o2, o3);
    *(uint2*)(op + i*4) = pk;
  }
}

extern "C" void kernel_launch(void* const* d_in, const int* in_sizes, int n_in,
                              void* d_out, int out_size, void* d_ws, size_t ws_size,
                              hipStream_t stream) {
  const float* x     = (const float*)d_in[0];
  const float* depth = (const float*)d_in[1];
  const int*   rpi   = (const int*)d_in[2];
  const float* n1w   = (const float*)d_in[3];
  const float* n1b   = (const float*)d_in[4];
  const float* qkvw  = (const float*)d_in[5];
  const float* qkvb  = (const float*)d_in[6];
  const float* dprjw = (const float*)d_in[7];
  const float* dprjb = (const float*)d_in[8];
  const float* rpb   = (const float*)d_in[9];
  const float* prjw  = (const float*)d_in[10];
  const float* prjb  = (const float*)d_in[11];
  const float* n2w   = (const float*)d_in[12];
  const float* n2b   = (const float*)d_in[13];
  const float* fc1w  = (const float*)d_in[14];
  const float* fc1b  = (const float*)d_in[15];
  const float* fc2w  = (const float*)d_in[16];
  const float* fc2b  = (const float*)d_in[17];

  char* ws = (char*)d_ws;
  unsigned short* xn  = (unsigned short*)(ws + 0);          // 12.6MB (dead after KV gemm)
  unsigned short* dn  = (unsigned short*)(ws + 12582912);   // 12.6MB (dead after Q gemm)
  unsigned short* xf  = (unsigned short*)(ws + 25165824);   // 12.6MB (dead after proj)
  unsigned short* kv  = (unsigned short*)(ws + 37748736);   // 25.2MB (dead after attn)
  unsigned short* h1  = (unsigned short*)(ws + 37748736);   //   overlays kv
  unsigned short* qm  = (unsigned short*)(ws + 62914560);   // 12.6MB (dead after attn)
  float*          r2  = (float*)(ws + 75497472);            // 25.2MB (no overlay)
  unsigned short* om  = (unsigned short*)(ws + 100663296);  // 12.6MB (dead after proj)
  unsigned short* n2  = (unsigned short*)(ws + 100663296);  //   overlays om (sequential kernels)
  unsigned short* kvw = (unsigned short*)(ws + 113246208);
  unsigned short* dpw = (unsigned short*)(ws + 113393664);
  unsigned short* pjw = (unsigned short*)(ws + 113467392);
  unsigned short* f1w = (unsigned short*)(ws + 113541120);
  unsigned short* f2w = (unsigned short*)(ws + 113688576);
  unsigned short* bt  = (unsigned short*)(ws + 113836032);  // 1769472B -> end 115605504 (round-6 proven)

  prep_all<<<5120, 256, 0, stream>>>(x, depth, n1w, n1b, qkvw, dprjw, prjw, fc1w, fc2w,
                                     rpi, rpb, xn, xf, dn, kvw, dpw, pjw, f1w, f2w, bt);
  gemm_kvq<<<2304, 256, 27648, stream>>>(xn, dn, kvw, dpw, qkvb + 192, dprjb, kv, qm);
  attn_k<<<768, 512, 0, stream>>>(qm, kv, bt, om);
  // r2 = om @ proj_w + b + xf   (f32 token-major)
  gemm2<<<768, 256, 34816, stream>>>(om, pjw, prjb, xf, nullptr, r2, 192, 192, 2);
  ln2_k<<<512, 256, 0, stream>>>(r2, n2w, n2b, n2);
  gemm2<<<1536, 256, 27648, stream>>>(n2, f1w, fc1b, nullptr, nullptr, h1, 192, 384, 1);
  gemm2<<<768, 256, 33792, stream>>>(h1, f2w, fc2b, nullptr, r2, d_out, 384, 192, 8);
}